// Round 1
// baseline (2720.694 us; speedup 1.0000x reference)
//
#include <hip/hip_runtime.h>
#include <math.h>

#define NB 16
#define SL 32

__device__ __forceinline__ float sigf(float x) { return 1.0f / (1.0f + expf(-x)); }

// ---------------- zero ----------------
__global__ void k_zero(float* __restrict__ p, int n) {
  int i = blockIdx.x * blockDim.x + threadIdx.x;
  if (i < n) p[i] = 0.0f;
}

// ---- generic f32 GEMM: out[r,g] = bias[g] + sum_k A[r,k]*W[g,k]  (A row-major lda, W row-major ldw)
// grid (N/64, M/64), block 256
__global__ __launch_bounds__(256)
void k_gemm(const float* __restrict__ A, int lda,
            const float* __restrict__ W, int ldw,
            const float* __restrict__ bias,
            float* __restrict__ out, int N, int K)
{
  __shared__ __align__(16) float sm[2 * 16 * 68];
  float* As = sm;
  float* Ws = sm + 16 * 68;
  const int tid = threadIdx.x;
  const int tx = tid & 15, ty = tid >> 4;
  const int g0 = blockIdx.x * 64, r0 = blockIdx.y * 64;
  float acc[4][4];
#pragma unroll
  for (int i = 0; i < 4; ++i)
#pragma unroll
    for (int j = 0; j < 4; ++j) acc[i][j] = 0.0f;
  const int ks = tid & 15, rr = tid >> 4;
  for (int kt = 0; kt < K; kt += 16) {
#pragma unroll
    for (int rep = 0; rep < 4; ++rep) {
      As[ks * 68 + rep * 16 + rr] = A[(size_t)(r0 + rep * 16 + rr) * lda + kt + ks];
      Ws[ks * 68 + rep * 16 + rr] = W[(size_t)(g0 + rep * 16 + rr) * ldw + kt + ks];
    }
    __syncthreads();
#pragma unroll
    for (int k = 0; k < 16; ++k) {
      const float4 a4 = *(const float4*)&As[k * 68 + ty * 4];
      const float4 w4 = *(const float4*)&Ws[k * 68 + tx * 4];
      const float av[4] = {a4.x, a4.y, a4.z, a4.w};
      const float wv[4] = {w4.x, w4.y, w4.z, w4.w};
#pragma unroll
      for (int i = 0; i < 4; ++i)
#pragma unroll
        for (int j = 0; j < 4; ++j) acc[i][j] += av[i] * wv[j];
    }
    __syncthreads();
  }
  float bvec[4] = {0.f, 0.f, 0.f, 0.f};
  if (bias) {
#pragma unroll
    for (int j = 0; j < 4; ++j) bvec[j] = bias[g0 + tx * 4 + j];
  }
#pragma unroll
  for (int i = 0; i < 4; ++i) {
    const int r = r0 + ty * 4 + i;
    float4 o;
    o.x = acc[i][0] + bvec[0];
    o.y = acc[i][1] + bvec[1];
    o.z = acc[i][2] + bvec[2];
    o.w = acc[i][3] + bvec[3];
    *(float4*)&out[(size_t)r * N + g0 + tx * 4] = o;
  }
}

// ---------------- one LSTM timestep, both directions ----------------
// grid (64, 2): x = j-tile (8 j each), y = dir. block 128 = 16 b * 8 j  (lane = b fastest)
__global__ __launch_bounds__(128)
void k_step(const float* __restrict__ Xf, const float* __restrict__ Xb,
            const float* __restrict__ Whf, const float* __restrict__ Whb,
            const float* __restrict__ bf, const float* __restrict__ bb,
            const int* __restrict__ len,
            float* __restrict__ hbuf, float* __restrict__ cbuf,
            float* __restrict__ hs, float* __restrict__ cs, int t)
{
  const int dir = blockIdx.y;
  const int jt = blockIdx.x;
  const int tid = threadIdx.x;
  const int b = tid & 15, j_loc = tid >> 4;
  const float* Wh = dir ? Whb : Whf;
  const float* bias = dir ? bb : bf;
  const float* X = dir ? Xb : Xf;
  const int pp = t & 1;
  const float* hp = hbuf + dir * 16384 + pp * 8192;
  const float* cp = cbuf + dir * 16384 + pp * 8192;
  float* hn = hbuf + dir * 16384 + (pp ^ 1) * 8192;
  float* cn = cbuf + dir * 16384 + (pp ^ 1) * 8192;
  __shared__ __align__(16) float hl[16 * 520];  // padded stride for bank spread, 16B aligned rows
  for (int i = tid; i < 8192; i += 128)
    hl[(i >> 9) * 520 + (i & 511)] = hp[i];
  __syncthreads();
  const int j = jt * 8 + j_loc;
  float acc0 = 0.f, acc1 = 0.f, acc2 = 0.f, acc3 = 0.f;
  const float4* h4 = (const float4*)(hl + b * 520);
  const float* w0 = Wh + (size_t)(0 * 512 + j) * 512;
  const float* w1 = Wh + (size_t)(1 * 512 + j) * 512;
  const float* w2 = Wh + (size_t)(2 * 512 + j) * 512;
  const float* w3 = Wh + (size_t)(3 * 512 + j) * 512;
  for (int w = 0; w < 128; ++w) {
    const float4 hv = h4[w];
    float4 a = *(const float4*)(w0 + w * 4);
    acc0 += hv.x * a.x + hv.y * a.y + hv.z * a.z + hv.w * a.w;
    a = *(const float4*)(w1 + w * 4);
    acc1 += hv.x * a.x + hv.y * a.y + hv.z * a.z + hv.w * a.w;
    a = *(const float4*)(w2 + w * 4);
    acc2 += hv.x * a.x + hv.y * a.y + hv.z * a.z + hv.w * a.w;
    a = *(const float4*)(w3 + w * 4);
    acc3 += hv.x * a.x + hv.y * a.y + hv.z * a.z + hv.w * a.w;
  }
  const int Lb = len[b];
  int xidx = t;
  if (dir) xidx = (t < Lb) ? (Lb - 1 - t) : t;
  const float* xr = X + (size_t)(b * SL + xidx) * 2048;
  const float gi = acc0 + xr[j] + bias[j];
  const float gf = acc1 + xr[512 + j] + bias[512 + j];
  const float gg = acc2 + xr[1024 + j] + bias[1024 + j];
  const float go = acc3 + xr[1536 + j] + bias[1536 + j];
  const float cprev = cp[b * 512 + j];
  const float cnew = sigf(gf) * cprev + sigf(gi) * tanhf(gg);
  const float hnew = sigf(go) * tanhf(cnew);
  hn[b * 512 + j] = hnew;
  cn[b * 512 + j] = cnew;
  const int pos = dir ? xidx : t;   // backward outputs scatter through the involutive reverse
  const int col = dir ? (512 + j) : j;
  hs[(size_t)(b * SL + pos) * 1024 + col] = hnew;
  cs[(size_t)(b * SL + pos) * 1024 + col] = cnew;
}

// ---------------- tree structure (argmax splits) ----------------
// grid 16 (one block per sentence), block 256
__global__ __launch_bounds__(256)
void k_tree(const float* __restrict__ E1, const float* __restrict__ Wr1,
            const float* __restrict__ Wr2, const int* __restrict__ len,
            int* __restrict__ meta)
{
  const int b = blockIdx.x;
  const int tid = threadIdx.x;
  __shared__ float e[32 * 257];
  __shared__ float w1p[256];
  __shared__ float w2s[256];
  __shared__ float sc[32];
  __shared__ float red[32 * 8];
  __shared__ int stk[40 * 3];
  __shared__ int ctrl[8];  // 0:sp 1:nn 2:s 3:e 4:nid
  for (int i = tid; i < 32 * 256; i += 256)
    e[(i >> 8) * 257 + (i & 255)] = E1[(size_t)(b * SL + (i >> 8)) * 256 + (i & 255)];
  w1p[tid] = Wr1[tid * 513 + 512];
  w2s[tid] = Wr2[tid];
  int* own = meta;
  int* lt = meta + 512;
  int* li = meta + 1024;
  int* rt = meta + 1536;
  int* ri = meta + 2048;
  int* dep = meta + 2560;
  int* nn = meta + 3072;
  if (tid < 32) dep[b * 32 + tid] = -1;
  if (tid == 0) {
    ctrl[0] = 1;
    ctrl[1] = 1;
    stk[0] = 0; stk[1] = len[b]; stk[2] = 0;
  }
  const int t_ = tid & 31, jg = tid >> 5;
  while (true) {
    __syncthreads();
    if (tid == 0) {
      int sp = ctrl[0];
      if (sp == 0) ctrl[4] = -1;
      else {
        sp--;
        ctrl[0] = sp;
        ctrl[2] = stk[sp * 3];
        ctrl[3] = stk[sp * 3 + 1];
        ctrl[4] = stk[sp * 3 + 2];
      }
    }
    __syncthreads();
    const int nid = ctrl[4];
    if (nid < 0) break;
    const int s = ctrl[2], eN = ctrl[3], l = eN - s;
    float part = 0.0f;
    if (t_ < l) {
      const float pos = 2.0f * (float)t_ / (float)l - 1.0f;
      const float* er = e + (s + t_) * 257;
      for (int q = jg * 32; q < jg * 32 + 32; ++q) {
        const float v = er[q] + pos * w1p[q];
        part += fmaxf(v, 0.0f) * w2s[q];
      }
    }
    red[t_ * 8 + jg] = part;
    __syncthreads();
    if (jg == 0 && t_ < l) {
      float su = 0.0f;
      for (int q = 0; q < 8; ++q) su += red[t_ * 8 + q];
      sc[t_] = su;
    }
    __syncthreads();
    if (tid == 0) {
      int k = 0;
      float best = sc[0];
      for (int q = 1; q < l; ++q)
        if (sc[q] > best) { best = sc[q]; k = q; }  // first-max tie-break, matches argmax
      const int m = b * 32 + nid;
      own[m] = s + k;
      int nn_ = ctrl[1], sp = ctrl[0];
      if (k == 0) { lt[m] = 0; li[m] = 0; }
      else if (k == 1) { lt[m] = 1; li[m] = s; }
      else {
        const int id = nn_++;
        lt[m] = 2; li[m] = id;
        stk[sp * 3] = s; stk[sp * 3 + 1] = s + k; stk[sp * 3 + 2] = id; sp++;
      }
      const int rl = l - k - 1;
      if (rl == 0) { rt[m] = 0; ri[m] = 0; }
      else if (rl == 1) { rt[m] = 1; ri[m] = s + k + 1; }
      else {
        const int id = nn_++;
        rt[m] = 2; ri[m] = id;
        stk[sp * 3] = s + k + 1; stk[sp * 3 + 1] = eN; stk[sp * 3 + 2] = id; sp++;
      }
      ctrl[0] = sp; ctrl[1] = nn_;
    }
  }
  __syncthreads();
  if (tid == 0) {
    const int n_ = ctrl[1];
    nn[b] = n_;
    for (int i = n_ - 1; i >= 0; --i) {  // children have larger ids -> already done
      const int m = b * 32 + i;
      int d = 1;
      if (lt[m] == 2) d = max(d, dep[b * 32 + li[m]] + 1);
      if (rt[m] == 2) d = max(d, dep[b * 32 + ri[m]] + 1);
      dep[m] = d;
    }
  }
}

// ---------------- build U = [hl_leaf|0 , hr_leaf|0 , hx] per node ----------------
// grid (32, 16): x = node id, y = sentence. block 256
__global__ __launch_bounds__(256)
void k_ubuild(const float* __restrict__ hs, const int* __restrict__ meta,
              float* __restrict__ U)
{
  const int id = blockIdx.x, b = blockIdx.y;
  const int tid = threadIdx.x;
  const int* own = meta;
  const int* lt = meta + 512;
  const int* li = meta + 1024;
  const int* rt = meta + 1536;
  const int* ri = meta + 2048;
  const int* nn = meta + 3072;
  const int m = b * 32 + id;
  float* u = U + (size_t)m * 3072;
  if (id >= nn[b]) {
    for (int i = tid; i < 3072; i += 256) u[i] = 0.0f;
    return;
  }
  const float* hl = (lt[m] == 1) ? hs + (size_t)(b * 32 + li[m]) * 1024 : nullptr;
  const float* hr = (rt[m] == 1) ? hs + (size_t)(b * 32 + ri[m]) * 1024 : nullptr;
  const float* hx = hs + (size_t)(b * 32 + own[m]) * 1024;
  for (int i = tid; i < 1024; i += 256) {
    u[i] = hl ? hl[i] : 0.0f;
    u[1024 + i] = hr ? hr[i] : 0.0f;
    u[2048 + i] = hx[i];
  }
}

// ---------------- one compose round: add internal-child links + gate ----------------
// grid 256 (4 j each), block 256 = 4 j * 64 lanes
__global__ __launch_bounds__(256)
void k_round(const float* __restrict__ Wc, const float* __restrict__ gB,
             const float* __restrict__ cs, const int* __restrict__ meta,
             float* __restrict__ nodeh, float* __restrict__ nodec, int r)
{
  const int* lt = meta + 512;
  const int* li = meta + 1024;
  const int* rt = meta + 1536;
  const int* ri = meta + 2048;
  const int* dep = meta + 2560;
  const int* nn = meta + 3072;
  const int tid = threadIdx.x;
  const int j_loc = tid >> 6, s = tid & 63;
  const int j = blockIdx.x * 4 + j_loc;

  int total = 0;
  for (int b = 0; b < NB; ++b) {
    const int n_ = nn[b];
    for (int n = 0; n < n_; ++n)
      if (dep[b * 32 + n] == r) total++;
  }
  if (total == 0) return;

  for (int c0 = 0; c0 < total; c0 += 8) {
    int ids[8];
    int mc = 0;
    {
      int cnt = 0;
      for (int b = 0; b < NB && mc < 8; ++b) {
        const int n_ = nn[b];
        for (int n = 0; n < n_ && mc < 8; ++n) {
          if (dep[b * 32 + n] == r) {
            if (cnt >= c0) ids[mc++] = b * 32 + n;
            cnt++;
          }
        }
      }
    }
    float acc[8][5];
#pragma unroll
    for (int m = 0; m < 8; ++m)
#pragma unroll
      for (int q = 0; q < 5; ++q) acc[m][q] = 0.0f;

    const float4 z4 = make_float4(0.f, 0.f, 0.f, 0.f);
    for (int side = 0; side < 2; ++side) {
      const float* hv[8];
#pragma unroll
      for (int m = 0; m < 8; ++m) hv[m] = nullptr;
      bool any = false;
      for (int m = 0; m < mc; ++m) {
        const int idx = ids[m];
        const int ct = side ? rt[idx] : lt[idx];
        const int ci = side ? ri[idx] : li[idx];
        if (ct == 2) { hv[m] = nodeh + (size_t)((idx & ~31) + ci) * 1024; any = true; }
      }
      if (!any) continue;
      for (int it = 0; it < 4; ++it) {
        const int w = it * 256 + s * 4;
        float4 h4[8];
#pragma unroll
        for (int m = 0; m < 8; ++m)
          h4[m] = hv[m] ? *(const float4*)(hv[m] + w) : z4;
#pragma unroll
        for (int q = 0; q < 5; ++q) {
          const float4 wv =
              *(const float4*)(Wc + (size_t)(q * 1024 + j) * 3072 + side * 1024 + w);
#pragma unroll
          for (int m = 0; m < 8; ++m)
            acc[m][q] += wv.x * h4[m].x + wv.y * h4[m].y + wv.z * h4[m].z + wv.w * h4[m].w;
        }
      }
    }
#pragma unroll
    for (int m = 0; m < 8; ++m)
#pragma unroll
      for (int q = 0; q < 5; ++q) {
        float v = acc[m][q];
        v += __shfl_down(v, 32);
        v += __shfl_down(v, 16);
        v += __shfl_down(v, 8);
        v += __shfl_down(v, 4);
        v += __shfl_down(v, 2);
        v += __shfl_down(v, 1);
        acc[m][q] = v;
      }
    if (s == 0) {
      for (int m = 0; m < mc; ++m) {
        const int idx = ids[m];
        const int base = idx & ~31;
        const float* gb = gB + (size_t)idx * 5120 + j;
        const float gi_ = gb[0] + acc[m][0];
        const float gfl = gb[1024] + acc[m][1];
        const float gfr = gb[2048] + acc[m][2];
        const float gu_ = gb[3072] + acc[m][3];
        const float go_ = gb[4096] + acc[m][4];
        float cl = 0.f, cr = 0.f;
        if (lt[idx] == 2) cl = nodec[(size_t)(base + li[idx]) * 1024 + j];
        else if (lt[idx] == 1) cl = cs[(size_t)(base + li[idx]) * 1024 + j];
        if (rt[idx] == 2) cr = nodec[(size_t)(base + ri[idx]) * 1024 + j];
        else if (rt[idx] == 1) cr = cs[(size_t)(base + ri[idx]) * 1024 + j];
        const float c = sigf(gfl) * cl + sigf(gfr) * cr + sigf(gi_) * tanhf(gu_);
        const float h = sigf(go_) * tanhf(c);
        nodeh[(size_t)idx * 1024 + j] = h;
        nodec[(size_t)idx * 1024 + j] = c;
      }
    }
  }
}

// ---------------- gather roots ----------------
__global__ void k_out(const float* __restrict__ nodeh, const float* __restrict__ nodec,
                      float* __restrict__ out)
{
  const int b = blockIdx.x;
  const int tid = threadIdx.x;
  for (int i = tid; i < 1024; i += 256) {
    out[b * 1024 + i] = nodeh[(size_t)(b * 32) * 1024 + i];          // root is node 0
    out[16384 + b * 1024 + i] = nodec[(size_t)(b * 32) * 1024 + i];
  }
}

extern "C" void kernel_launch(void* const* d_in, const int* in_sizes, int n_in,
                              void* d_out, int out_size, void* d_ws, size_t ws_size,
                              hipStream_t stream) {
  const float* emb = (const float*)d_in[0];
  const int* len = (const int*)d_in[1];
  const float* Wihf = (const float*)d_in[2];
  const float* Whhf = (const float*)d_in[3];
  const float* bf = (const float*)d_in[4];
  const float* Wihb = (const float*)d_in[5];
  const float* Whhb = (const float*)d_in[6];
  const float* bb = (const float*)d_in[7];
  const float* Wr1 = (const float*)d_in[8];
  const float* Wr2 = (const float*)d_in[9];
  const float* Wc = (const float*)d_in[10];
  const float* bc = (const float*)d_in[11];
  float* out = (float*)d_out;

  float* ws = (float*)d_ws;
  float* Xf = ws;                   // 16*32*2048
  float* Xb = Xf + 1048576;         // 16*32*2048
  float* hs = Xb + 1048576;         // 16*32*1024
  float* cs = hs + 524288;          // 16*32*1024
  float* hbuf = cs + 524288;        // 2dir*2pp*16*512
  float* cbuf = hbuf + 32768;
  float* E1 = cbuf + 32768;         // 16*32*256
  float* U = E1 + 131072;           // 512*3072
  float* gB = U + 1572864;          // 512*5120
  float* nodeh = gB + 2621440;      // 16*32*1024
  float* nodec = nodeh + 524288;
  int* meta = (int*)(nodec + 524288);  // ~3.1K ints

  // zero ping-pong state
  k_zero<<<256, 256, 0, stream>>>(hbuf, 65536);
  // input projections + rank projection
  k_gemm<<<dim3(32, 8), 256, 0, stream>>>(emb, 512, Wihf, 512, nullptr, Xf, 2048, 512);
  k_gemm<<<dim3(32, 8), 256, 0, stream>>>(emb, 512, Wihb, 512, nullptr, Xb, 2048, 512);
  k_gemm<<<dim3(4, 8), 256, 0, stream>>>(emb, 512, Wr1, 513, nullptr, E1, 256, 512);
  // recurrent scan
  for (int t = 0; t < SL; ++t)
    k_step<<<dim3(64, 2), 128, 0, stream>>>(Xf, Xb, Whhf, Whhb, bf, bb, len,
                                            hbuf, cbuf, hs, cs, t);
  // tree structure + depths
  k_tree<<<16, 256, 0, stream>>>(E1, Wr1, Wr2, len, meta);
  // precomputable part of every compose (own + leaf children) in one big GEMM
  k_ubuild<<<dim3(32, 16), 256, 0, stream>>>(hs, meta, U);
  k_gemm<<<dim3(80, 8), 256, 0, stream>>>(U, 3072, Wc, 3072, bc, gB, 5120, 3072);
  // depth-ordered compose rounds (max possible depth = 31)
  for (int r = 1; r <= 31; ++r)
    k_round<<<256, 256, 0, stream>>>(Wc, gB, cs, meta, nodeh, nodec, r);
  k_out<<<16, 256, 0, stream>>>(nodeh, nodec, out);
}

// Round 2
// 2609.049 us; speedup vs baseline: 1.0428x; 1.0428x over previous
//
#include <hip/hip_runtime.h>
#include <math.h>

#define NB 16
#define SL 32
#define H5 5120
#define K3 3072

typedef __attribute__((ext_vector_type(8))) short short8;
typedef __attribute__((ext_vector_type(4))) float floatx4;

__device__ __forceinline__ float sigf(float x) { return 1.0f / (1.0f + expf(-x)); }

__device__ __forceinline__ unsigned short f2bf(float x) {
  union { float f; unsigned int u; } v;
  v.f = x;
  unsigned int r = v.u + 0x7FFFu + ((v.u >> 16) & 1u);
  return (unsigned short)(r >> 16);
}

// ---------------- zero ----------------
__global__ void k_zero(float* __restrict__ p, int n) {
  int i = blockIdx.x * blockDim.x + threadIdx.x;
  if (i < n) p[i] = 0.0f;
}

// ---- generic f32 GEMM: out[r,g] = sum_k A[r,k]*W[g,k]
__global__ __launch_bounds__(256)
void k_gemm(const float* __restrict__ A, int lda,
            const float* __restrict__ W, int ldw,
            float* __restrict__ out, int N, int K)
{
  __shared__ __align__(16) float sm[2 * 16 * 68];
  float* As = sm;
  float* Ws = sm + 16 * 68;
  const int tid = threadIdx.x;
  const int tx = tid & 15, ty = tid >> 4;
  const int g0 = blockIdx.x * 64, r0 = blockIdx.y * 64;
  float acc[4][4];
#pragma unroll
  for (int i = 0; i < 4; ++i)
#pragma unroll
    for (int j = 0; j < 4; ++j) acc[i][j] = 0.0f;
  const int ks = tid & 15, rr = tid >> 4;
  for (int kt = 0; kt < K; kt += 16) {
#pragma unroll
    for (int rep = 0; rep < 4; ++rep) {
      As[ks * 68 + rep * 16 + rr] = A[(size_t)(r0 + rep * 16 + rr) * lda + kt + ks];
      Ws[ks * 68 + rep * 16 + rr] = W[(size_t)(g0 + rep * 16 + rr) * ldw + kt + ks];
    }
    __syncthreads();
#pragma unroll
    for (int k = 0; k < 16; ++k) {
      const float4 a4 = *(const float4*)&As[k * 68 + ty * 4];
      const float4 w4 = *(const float4*)&Ws[k * 68 + tx * 4];
      const float av[4] = {a4.x, a4.y, a4.z, a4.w};
      const float wv[4] = {w4.x, w4.y, w4.z, w4.w};
#pragma unroll
      for (int i = 0; i < 4; ++i)
#pragma unroll
        for (int j = 0; j < 4; ++j) acc[i][j] += av[i] * wv[j];
    }
    __syncthreads();
  }
#pragma unroll
  for (int i = 0; i < 4; ++i) {
    const int r = r0 + ty * 4 + i;
    float4 o;
    o.x = acc[i][0];
    o.y = acc[i][1];
    o.z = acc[i][2];
    o.w = acc[i][3];
    *(float4*)&out[(size_t)r * N + g0 + tx * 4] = o;
  }
}

// ---------------- bf16 MFMA GEMM: gB[r,g] = bc[g] + sum_k U[r,k]*Wc[g,k] ----------------
// M=512, N=5120, K=3072. grid (40, 4), block 256 (4 waves, 2x2, each 64x64)
__global__ __launch_bounds__(256)
void k_mfma_gemm(const unsigned short* __restrict__ U, const float* __restrict__ Wc,
                 const float* __restrict__ bc, float* __restrict__ gB)
{
  __shared__ __align__(16) unsigned short As[128 * 32];
  __shared__ __align__(16) unsigned short Bs[128 * 32];
  const int tid = threadIdx.x;
  const int g0 = blockIdx.x * 128;
  const int r0 = blockIdx.y * 128;
  const int wave = tid >> 6, lane = tid & 63;
  const int wm = wave >> 1, wn = wave & 1;
  const int l15 = lane & 15, quad = lane >> 4;
  floatx4 acc[4][4];
#pragma unroll
  for (int mt = 0; mt < 4; ++mt)
#pragma unroll
    for (int nt = 0; nt < 4; ++nt) acc[mt][nt] = (floatx4){0.f, 0.f, 0.f, 0.f};

  for (int kt = 0; kt < K3; kt += 32) {
    __syncthreads();
    // stage A (bf16): 128 rows x 32 k, 2 x 16B per thread
#pragma unroll
    for (int p = 0; p < 2; ++p) {
      const int i = tid + p * 256;
      const int row = i >> 2, q = i & 3;
      *(uint4*)&As[row * 32 + q * 8] = *(const uint4*)&U[(size_t)(r0 + row) * K3 + kt + q * 8];
    }
    // stage B (f32 -> bf16): 128 rows x 32 k, 4 x (4 floats) per thread
#pragma unroll
    for (int p = 0; p < 4; ++p) {
      const int i = tid + p * 256;
      const int row = i >> 3, f = i & 7;
      const float4 v = *(const float4*)&Wc[(size_t)(g0 + row) * K3 + kt + f * 4];
      ushort4 o;
      o.x = f2bf(v.x); o.y = f2bf(v.y); o.z = f2bf(v.z); o.w = f2bf(v.w);
      *(ushort4*)&Bs[row * 32 + f * 4] = o;
    }
    __syncthreads();
    short8 af[4], bfr[4];
#pragma unroll
    for (int mt = 0; mt < 4; ++mt)
      af[mt] = *(const short8*)&As[(wm * 64 + mt * 16 + l15) * 32 + quad * 8];
#pragma unroll
    for (int nt = 0; nt < 4; ++nt)
      bfr[nt] = *(const short8*)&Bs[(wn * 64 + nt * 16 + l15) * 32 + quad * 8];
#pragma unroll
    for (int mt = 0; mt < 4; ++mt)
#pragma unroll
      for (int nt = 0; nt < 4; ++nt)
        acc[mt][nt] = __builtin_amdgcn_mfma_f32_16x16x32_bf16(af[mt], bfr[nt], acc[mt][nt], 0, 0, 0);
  }
  // epilogue: D[row=quad*4+i][col=l15] + bias
#pragma unroll
  for (int nt = 0; nt < 4; ++nt) {
    const int col = g0 + wn * 64 + nt * 16 + l15;
    const float bias = bc[col];
#pragma unroll
    for (int mt = 0; mt < 4; ++mt) {
#pragma unroll
      for (int i = 0; i < 4; ++i) {
        const int row = r0 + wm * 64 + mt * 16 + quad * 4 + i;
        gB[(size_t)row * H5 + col] = acc[mt][nt][i] + bias;
      }
    }
  }
}

// ---------------- one LSTM timestep, both directions ----------------
__global__ __launch_bounds__(128)
void k_step(const float* __restrict__ Xf, const float* __restrict__ Xb,
            const float* __restrict__ Whf, const float* __restrict__ Whb,
            const float* __restrict__ bf, const float* __restrict__ bb,
            const int* __restrict__ len,
            float* __restrict__ hbuf, float* __restrict__ cbuf,
            float* __restrict__ hs, float* __restrict__ cs, int t)
{
  const int dir = blockIdx.y;
  const int jt = blockIdx.x;
  const int tid = threadIdx.x;
  const int b = tid & 15, j_loc = tid >> 4;
  const float* Wh = dir ? Whb : Whf;
  const float* bias = dir ? bb : bf;
  const float* X = dir ? Xb : Xf;
  const int pp = t & 1;
  const float* hp = hbuf + dir * 16384 + pp * 8192;
  const float* cp = cbuf + dir * 16384 + pp * 8192;
  float* hn = hbuf + dir * 16384 + (pp ^ 1) * 8192;
  float* cn = cbuf + dir * 16384 + (pp ^ 1) * 8192;
  __shared__ __align__(16) float hl[16 * 520];
  for (int i = tid; i < 8192; i += 128)
    hl[(i >> 9) * 520 + (i & 511)] = hp[i];
  __syncthreads();
  const int j = jt * 8 + j_loc;
  float acc0 = 0.f, acc1 = 0.f, acc2 = 0.f, acc3 = 0.f;
  const float4* h4 = (const float4*)(hl + b * 520);
  const float* w0 = Wh + (size_t)(0 * 512 + j) * 512;
  const float* w1 = Wh + (size_t)(1 * 512 + j) * 512;
  const float* w2 = Wh + (size_t)(2 * 512 + j) * 512;
  const float* w3 = Wh + (size_t)(3 * 512 + j) * 512;
  for (int w = 0; w < 128; ++w) {
    const float4 hv = h4[w];
    float4 a = *(const float4*)(w0 + w * 4);
    acc0 += hv.x * a.x + hv.y * a.y + hv.z * a.z + hv.w * a.w;
    a = *(const float4*)(w1 + w * 4);
    acc1 += hv.x * a.x + hv.y * a.y + hv.z * a.z + hv.w * a.w;
    a = *(const float4*)(w2 + w * 4);
    acc2 += hv.x * a.x + hv.y * a.y + hv.z * a.z + hv.w * a.w;
    a = *(const float4*)(w3 + w * 4);
    acc3 += hv.x * a.x + hv.y * a.y + hv.z * a.z + hv.w * a.w;
  }
  const int Lb = len[b];
  int xidx = t;
  if (dir) xidx = (t < Lb) ? (Lb - 1 - t) : t;
  const float* xr = X + (size_t)(b * SL + xidx) * 2048;
  const float gi = acc0 + xr[j] + bias[j];
  const float gf = acc1 + xr[512 + j] + bias[512 + j];
  const float gg = acc2 + xr[1024 + j] + bias[1024 + j];
  const float go = acc3 + xr[1536 + j] + bias[1536 + j];
  const float cprev = cp[b * 512 + j];
  const float cnew = sigf(gf) * cprev + sigf(gi) * tanhf(gg);
  const float hnew = sigf(go) * tanhf(cnew);
  hn[b * 512 + j] = hnew;
  cn[b * 512 + j] = cnew;
  const int pos = dir ? xidx : t;
  const int col = dir ? (512 + j) : j;
  hs[(size_t)(b * SL + pos) * 1024 + col] = hnew;
  cs[(size_t)(b * SL + pos) * 1024 + col] = cnew;
}

// ---------------- tree structure (argmax splits) + depth lists ----------------
__global__ __launch_bounds__(256)
void k_tree(const float* __restrict__ E1, const float* __restrict__ Wr1,
            const float* __restrict__ Wr2, const int* __restrict__ len,
            int* __restrict__ meta)
{
  const int b = blockIdx.x;
  const int tid = threadIdx.x;
  __shared__ float e[32 * 257];
  __shared__ float w1p[256];
  __shared__ float w2s[256];
  __shared__ float sc[32];
  __shared__ float red[32 * 8];
  __shared__ int stk[40 * 3];
  __shared__ int ctrl[8];
  for (int i = tid; i < 32 * 256; i += 256)
    e[(i >> 8) * 257 + (i & 255)] = E1[(size_t)(b * SL + (i >> 8)) * 256 + (i & 255)];
  w1p[tid] = Wr1[tid * 513 + 512];
  w2s[tid] = Wr2[tid];
  int* own = meta;
  int* lt = meta + 512;
  int* li = meta + 1024;
  int* rt = meta + 1536;
  int* ri = meta + 2048;
  int* dep = meta + 2560;
  int* nn = meta + 3072;
  int* dcnt = meta + 3088;
  int* dlist = meta + 3120;
  if (tid < 32) dep[b * 32 + tid] = -1;
  if (tid == 0) {
    ctrl[0] = 1;
    ctrl[1] = 1;
    stk[0] = 0; stk[1] = len[b]; stk[2] = 0;
  }
  const int t_ = tid & 31, jg = tid >> 5;
  while (true) {
    __syncthreads();
    if (tid == 0) {
      int sp = ctrl[0];
      if (sp == 0) ctrl[4] = -1;
      else {
        sp--;
        ctrl[0] = sp;
        ctrl[2] = stk[sp * 3];
        ctrl[3] = stk[sp * 3 + 1];
        ctrl[4] = stk[sp * 3 + 2];
      }
    }
    __syncthreads();
    const int nid = ctrl[4];
    if (nid < 0) break;
    const int s = ctrl[2], eN = ctrl[3], l = eN - s;
    float part = 0.0f;
    if (t_ < l) {
      const float pos = 2.0f * (float)t_ / (float)l - 1.0f;
      const float* er = e + (s + t_) * 257;
      for (int q = jg * 32; q < jg * 32 + 32; ++q) {
        const float v = er[q] + pos * w1p[q];
        part += fmaxf(v, 0.0f) * w2s[q];
      }
    }
    red[t_ * 8 + jg] = part;
    __syncthreads();
    if (jg == 0 && t_ < l) {
      float su = 0.0f;
      for (int q = 0; q < 8; ++q) su += red[t_ * 8 + q];
      sc[t_] = su;
    }
    __syncthreads();
    if (tid == 0) {
      int k = 0;
      float best = sc[0];
      for (int q = 1; q < l; ++q)
        if (sc[q] > best) { best = sc[q]; k = q; }
      const int m = b * 32 + nid;
      own[m] = s + k;
      int nn_ = ctrl[1], sp = ctrl[0];
      if (k == 0) { lt[m] = 0; li[m] = 0; }
      else if (k == 1) { lt[m] = 1; li[m] = s; }
      else {
        const int id = nn_++;
        lt[m] = 2; li[m] = id;
        stk[sp * 3] = s; stk[sp * 3 + 1] = s + k; stk[sp * 3 + 2] = id; sp++;
      }
      const int rl = l - k - 1;
      if (rl == 0) { rt[m] = 0; ri[m] = 0; }
      else if (rl == 1) { rt[m] = 1; ri[m] = s + k + 1; }
      else {
        const int id = nn_++;
        rt[m] = 2; ri[m] = id;
        stk[sp * 3] = s + k + 1; stk[sp * 3 + 1] = eN; stk[sp * 3 + 2] = id; sp++;
      }
      ctrl[0] = sp; ctrl[1] = nn_;
    }
  }
  __syncthreads();
  if (tid == 0) {
    const int n_ = ctrl[1];
    nn[b] = n_;
    for (int i = n_ - 1; i >= 0; --i) {
      const int m = b * 32 + i;
      int d = 1;
      if (lt[m] == 2) d = max(d, dep[b * 32 + li[m]] + 1);
      if (rt[m] == 2) d = max(d, dep[b * 32 + ri[m]] + 1);
      dep[m] = d;
    }
    for (int i = 0; i < n_; ++i) {
      const int r = dep[b * 32 + i];
      const int idx = atomicAdd(&dcnt[r], 1);
      dlist[r * 512 + idx] = b * 32 + i;
    }
  }
}

// ---------------- build U (bf16) = [hl_leaf|0 , hr_leaf|0 , hx] per node ----------------
__global__ __launch_bounds__(256)
void k_ubuild(const float* __restrict__ hs, const int* __restrict__ meta,
              unsigned short* __restrict__ U)
{
  const int id = blockIdx.x, b = blockIdx.y;
  const int tid = threadIdx.x;
  const int* own = meta;
  const int* lt = meta + 512;
  const int* li = meta + 1024;
  const int* rt = meta + 1536;
  const int* ri = meta + 2048;
  const int* nn = meta + 3072;
  const int m = b * 32 + id;
  unsigned short* u = U + (size_t)m * K3;
  if (id >= nn[b]) {
    for (int i = tid; i < K3; i += 256) u[i] = 0;
    return;
  }
  const float* hl = (lt[m] == 1) ? hs + (size_t)(b * 32 + li[m]) * 1024 : nullptr;
  const float* hr = (rt[m] == 1) ? hs + (size_t)(b * 32 + ri[m]) * 1024 : nullptr;
  const float* hx = hs + (size_t)(b * 32 + own[m]) * 1024;
  for (int i = tid; i < 1024; i += 256) {
    u[i] = hl ? f2bf(hl[i]) : 0;
    u[1024 + i] = hr ? f2bf(hr[i]) : 0;
    u[2048 + i] = f2bf(hx[i]);
  }
}

// ---------------- per-depth link GEMM: gB[node] += Wc[:, :2048] . [hl_int|0, hr_int|0] ----------------
// grid (80, 8): x = gate tile (64), y = node tile (64). block 256.
__global__ __launch_bounds__(256)
void k_linkgemm(const float* __restrict__ Wc, const int* __restrict__ meta,
                const float* __restrict__ nodeh, float* __restrict__ gB, int r)
{
  const int* lt = meta + 512;
  const int* li = meta + 1024;
  const int* rt = meta + 1536;
  const int* ri = meta + 2048;
  const int* dcnt = meta + 3088;
  const int* dlist = meta + 3120;
  const int cnt = dcnt[r];
  const int m0 = blockIdx.y * 64;
  if (m0 >= cnt) return;
  __shared__ __align__(16) float sm[2 * 16 * 68];
  __shared__ int sofs[2][64];
  __shared__ int snode[64];
  float* As = sm;
  float* Ws = sm + 16 * 68;
  const int tid = threadIdx.x;
  if (tid < 64) {
    int ofs_l = -1, ofs_r = -1, node = -1;
    const int m = m0 + tid;
    if (m < cnt) {
      node = dlist[r * 512 + m];
      const int base = node & ~31;
      if (lt[node] == 2) ofs_l = (base + li[node]) * 1024;
      if (rt[node] == 2) ofs_r = (base + ri[node]) * 1024;
    }
    snode[tid] = node;
    sofs[0][tid] = ofs_l;
    sofs[1][tid] = ofs_r;
  }
  __syncthreads();
  const int g0 = blockIdx.x * 64;
  const int tx = tid & 15, ty = tid >> 4;
  const int ks = tid & 15, rr = tid >> 4;
  float acc[4][4];
#pragma unroll
  for (int i = 0; i < 4; ++i)
#pragma unroll
    for (int j = 0; j < 4; ++j) acc[i][j] = 0.0f;
  for (int kt = 0; kt < 2048; kt += 16) {
    const int side = kt >> 10;
    const int kk = (kt & 1023) + ks;
#pragma unroll
    for (int rep = 0; rep < 4; ++rep) {
      const int row = rep * 16 + rr;
      const int ofs = sofs[side][row];
      As[ks * 68 + row] = (ofs >= 0) ? nodeh[(size_t)ofs + kk] : 0.0f;
      Ws[ks * 68 + row] = Wc[(size_t)(g0 + row) * K3 + kt + ks];
    }
    __syncthreads();
#pragma unroll
    for (int k = 0; k < 16; ++k) {
      const float4 a4 = *(const float4*)&As[k * 68 + ty * 4];
      const float4 w4 = *(const float4*)&Ws[k * 68 + tx * 4];
      const float av[4] = {a4.x, a4.y, a4.z, a4.w};
      const float wv[4] = {w4.x, w4.y, w4.z, w4.w};
#pragma unroll
      for (int i = 0; i < 4; ++i)
#pragma unroll
        for (int j = 0; j < 4; ++j) acc[i][j] += av[i] * wv[j];
    }
    __syncthreads();
  }
#pragma unroll
  for (int i = 0; i < 4; ++i) {
    const int m = m0 + ty * 4 + i;
    if (m < cnt) {
      const int node = snode[ty * 4 + i];
      float* gp = &gB[(size_t)node * H5 + g0 + tx * 4];
      float4 o = *(const float4*)gp;
      o.x += acc[i][0];
      o.y += acc[i][1];
      o.z += acc[i][2];
      o.w += acc[i][3];
      *(float4*)gp = o;
    }
  }
}

// ---------------- per-depth gating ----------------
__global__ void k_gate(const float* __restrict__ gB, const float* __restrict__ cs,
                       const int* __restrict__ meta, float* __restrict__ nodeh,
                       float* __restrict__ nodec, int r)
{
  const int* lt = meta + 512;
  const int* li = meta + 1024;
  const int* rt = meta + 1536;
  const int* ri = meta + 2048;
  const int* dcnt = meta + 3088;
  const int* dlist = meta + 3120;
  const int cnt = dcnt[r];
  const int m = blockIdx.x;
  if (m >= cnt) return;
  const int node = dlist[r * 512 + m];
  const int base = node & ~31;
  const int ltv = lt[node], rtv = rt[node];
  const float* clp = (ltv == 2) ? &nodec[(size_t)(base + li[node]) * 1024]
                   : (ltv == 1) ? &cs[(size_t)(base + li[node]) * 1024] : nullptr;
  const float* crp = (rtv == 2) ? &nodec[(size_t)(base + ri[node]) * 1024]
                   : (rtv == 1) ? &cs[(size_t)(base + ri[node]) * 1024] : nullptr;
  const float* g = &gB[(size_t)node * H5];
  for (int j = threadIdx.x; j < 1024; j += 256) {
    const float gi = g[j];
    const float gfl = g[1024 + j];
    const float gfr = g[2048 + j];
    const float gu = g[3072 + j];
    const float go = g[4096 + j];
    const float cl = clp ? clp[j] : 0.0f;
    const float cr = crp ? crp[j] : 0.0f;
    const float c = sigf(gfl) * cl + sigf(gfr) * cr + sigf(gi) * tanhf(gu);
    const float h = sigf(go) * tanhf(c);
    nodeh[(size_t)node * 1024 + j] = h;
    nodec[(size_t)node * 1024 + j] = c;
  }
}

// ---------------- gather roots ----------------
__global__ void k_out(const float* __restrict__ nodeh, const float* __restrict__ nodec,
                      float* __restrict__ out)
{
  const int b = blockIdx.x;
  const int tid = threadIdx.x;
  for (int i = tid; i < 1024; i += 256) {
    out[b * 1024 + i] = nodeh[(size_t)(b * 32) * 1024 + i];
    out[16384 + b * 1024 + i] = nodec[(size_t)(b * 32) * 1024 + i];
  }
}

extern "C" void kernel_launch(void* const* d_in, const int* in_sizes, int n_in,
                              void* d_out, int out_size, void* d_ws, size_t ws_size,
                              hipStream_t stream) {
  const float* emb = (const float*)d_in[0];
  const int* len = (const int*)d_in[1];
  const float* Wihf = (const float*)d_in[2];
  const float* Whhf = (const float*)d_in[3];
  const float* bf = (const float*)d_in[4];
  const float* Wihb = (const float*)d_in[5];
  const float* Whhb = (const float*)d_in[6];
  const float* bb = (const float*)d_in[7];
  const float* Wr1 = (const float*)d_in[8];
  const float* Wr2 = (const float*)d_in[9];
  const float* Wc = (const float*)d_in[10];
  const float* bc = (const float*)d_in[11];
  float* out = (float*)d_out;

  float* ws = (float*)d_ws;
  float* Xf = ws;                     // 16*32*2048
  float* Xb = Xf + 1048576;           // 16*32*2048
  float* hs = Xb + 1048576;           // 16*32*1024
  float* cs = hs + 524288;            // 16*32*1024
  float* hbuf = cs + 524288;          // 2*2*16*512
  float* cbuf = hbuf + 32768;
  float* E1 = cbuf + 32768;           // 16*32*256
  unsigned short* U = (unsigned short*)(E1 + 131072);   // 512*3072 bf16 (occupies old slot)
  float* gB = (float*)(U) + 1572864;  // 512*5120 f32 (slot preserved)
  float* nodeh = gB + 2621440;        // 16*32*1024
  float* nodec = nodeh + 524288;
  int* meta = (int*)(nodec + 524288); // own/lt/li/rt/ri/dep/nn/dcnt/dlist ~ 20K ints

  // zero LSTM ping-pong state + per-depth counters
  k_zero<<<256, 256, 0, stream>>>(hbuf, 65536);
  k_zero<<<1, 32, 0, stream>>>((float*)(meta + 3088), 32);
  // input projections + rank projection
  k_gemm<<<dim3(32, 8), 256, 0, stream>>>(emb, 512, Wihf, 512, Xf, 2048, 512);
  k_gemm<<<dim3(32, 8), 256, 0, stream>>>(emb, 512, Wihb, 512, Xb, 2048, 512);
  k_gemm<<<dim3(4, 8), 256, 0, stream>>>(emb, 512, Wr1, 513, E1, 256, 512);
  // recurrent scan
  for (int t = 0; t < SL; ++t)
    k_step<<<dim3(64, 2), 128, 0, stream>>>(Xf, Xb, Whhf, Whhb, bf, bb, len,
                                            hbuf, cbuf, hs, cs, t);
  // tree structure + depth lists
  k_tree<<<16, 256, 0, stream>>>(E1, Wr1, Wr2, len, meta);
  // precomputable part of every compose (own + leaf children) via bf16 MFMA
  k_ubuild<<<dim3(32, 16), 256, 0, stream>>>(hs, meta, U);
  k_mfma_gemm<<<dim3(40, 4), 256, 0, stream>>>(U, Wc, bc, gB);
  // depth-ordered compose rounds
  for (int r = 1; r <= 31; ++r) {
    k_linkgemm<<<dim3(80, 8), 256, 0, stream>>>(Wc, meta, nodeh, gB, r);
    k_gate<<<512, 256, 0, stream>>>(gB, cs, meta, nodeh, nodec, r);
  }
  k_out<<<16, 256, 0, stream>>>(nodeh, nodec, out);
}

// Round 3
// 1515.032 us; speedup vs baseline: 1.7958x; 1.7221x over previous
//
#include <hip/hip_runtime.h>
#include <math.h>

#define NB 16
#define SL 32
#define H5 5120
#define K3 3072

typedef __attribute__((ext_vector_type(8))) short short8;
typedef __attribute__((ext_vector_type(4))) float floatx4;

__device__ __forceinline__ float sigf(float x) { return 1.0f / (1.0f + expf(-x)); }

__device__ __forceinline__ unsigned short f2bf(float x) {
  union { float f; unsigned int u; } v;
  v.f = x;
  unsigned int r = v.u + 0x7FFFu + ((v.u >> 16) & 1u);
  return (unsigned short)(r >> 16);
}

// meta layout (ints):
//  own 0, lt 512, li 1024, rt 1536, ri 2048, dep 2560, nn 3072(16),
//  dcnt 3088(32), lcnt 3120(32), dlist 3152(32*512), llist 19536(32*512)

// ---------------- zero ----------------
__global__ void k_zero(float* __restrict__ p, int n) {
  int i = blockIdx.x * blockDim.x + threadIdx.x;
  if (i < n) p[i] = 0.0f;
}

// ---- generic f32 GEMM: out[r,g] = sum_k A[r,k]*W[g,k]
__global__ __launch_bounds__(256)
void k_gemm(const float* __restrict__ A, int lda,
            const float* __restrict__ W, int ldw,
            float* __restrict__ out, int N, int K)
{
  __shared__ __align__(16) float sm[2 * 16 * 68];
  float* As = sm;
  float* Ws = sm + 16 * 68;
  const int tid = threadIdx.x;
  const int tx = tid & 15, ty = tid >> 4;
  const int g0 = blockIdx.x * 64, r0 = blockIdx.y * 64;
  float acc[4][4];
#pragma unroll
  for (int i = 0; i < 4; ++i)
#pragma unroll
    for (int j = 0; j < 4; ++j) acc[i][j] = 0.0f;
  const int ks = tid & 15, rr = tid >> 4;
  for (int kt = 0; kt < K; kt += 16) {
#pragma unroll
    for (int rep = 0; rep < 4; ++rep) {
      As[ks * 68 + rep * 16 + rr] = A[(size_t)(r0 + rep * 16 + rr) * lda + kt + ks];
      Ws[ks * 68 + rep * 16 + rr] = W[(size_t)(g0 + rep * 16 + rr) * ldw + kt + ks];
    }
    __syncthreads();
#pragma unroll
    for (int k = 0; k < 16; ++k) {
      const float4 a4 = *(const float4*)&As[k * 68 + ty * 4];
      const float4 w4 = *(const float4*)&Ws[k * 68 + tx * 4];
      const float av[4] = {a4.x, a4.y, a4.z, a4.w};
      const float wv[4] = {w4.x, w4.y, w4.z, w4.w};
#pragma unroll
      for (int i = 0; i < 4; ++i)
#pragma unroll
        for (int j = 0; j < 4; ++j) acc[i][j] += av[i] * wv[j];
    }
    __syncthreads();
  }
#pragma unroll
  for (int i = 0; i < 4; ++i) {
    const int r = r0 + ty * 4 + i;
    float4 o;
    o.x = acc[i][0];
    o.y = acc[i][1];
    o.z = acc[i][2];
    o.w = acc[i][3];
    *(float4*)&out[(size_t)r * N + g0 + tx * 4] = o;
  }
}

// ---------------- bf16 MFMA GEMM: gB[r,g] = bc[g] + sum_k U[r,k]*Wc[g,k] ----------------
// M=512, N=5120, K=3072. grid (40, 4), block 256 (4 waves, 2x2, each 64x64)
// LDS row stride 40 (bf16): 80B rows -> 2-way bank aliasing only.
__global__ __launch_bounds__(256)
void k_mfma_gemm(const unsigned short* __restrict__ U, const float* __restrict__ Wc,
                 const float* __restrict__ bc, float* __restrict__ gB)
{
  __shared__ __align__(16) unsigned short As[128 * 40];
  __shared__ __align__(16) unsigned short Bs[128 * 40];
  const int tid = threadIdx.x;
  const int g0 = blockIdx.x * 128;
  const int r0 = blockIdx.y * 128;
  const int wave = tid >> 6, lane = tid & 63;
  const int wm = wave >> 1, wn = wave & 1;
  const int l15 = lane & 15, quad = lane >> 4;
  floatx4 acc[4][4];
#pragma unroll
  for (int mt = 0; mt < 4; ++mt)
#pragma unroll
    for (int nt = 0; nt < 4; ++nt) acc[mt][nt] = (floatx4){0.f, 0.f, 0.f, 0.f};

  for (int kt = 0; kt < K3; kt += 32) {
    __syncthreads();
#pragma unroll
    for (int p = 0; p < 2; ++p) {
      const int i = tid + p * 256;
      const int row = i >> 2, q = i & 3;
      *(uint4*)&As[row * 40 + q * 8] = *(const uint4*)&U[(size_t)(r0 + row) * K3 + kt + q * 8];
    }
#pragma unroll
    for (int p = 0; p < 4; ++p) {
      const int i = tid + p * 256;
      const int row = i >> 3, f = i & 7;
      const float4 v = *(const float4*)&Wc[(size_t)(g0 + row) * K3 + kt + f * 4];
      ushort4 o;
      o.x = f2bf(v.x); o.y = f2bf(v.y); o.z = f2bf(v.z); o.w = f2bf(v.w);
      *(ushort4*)&Bs[row * 40 + f * 4] = o;
    }
    __syncthreads();
    short8 af[4], bfr[4];
#pragma unroll
    for (int mt = 0; mt < 4; ++mt)
      af[mt] = *(const short8*)&As[(wm * 64 + mt * 16 + l15) * 40 + quad * 8];
#pragma unroll
    for (int nt = 0; nt < 4; ++nt)
      bfr[nt] = *(const short8*)&Bs[(wn * 64 + nt * 16 + l15) * 40 + quad * 8];
#pragma unroll
    for (int mt = 0; mt < 4; ++mt)
#pragma unroll
      for (int nt = 0; nt < 4; ++nt)
        acc[mt][nt] = __builtin_amdgcn_mfma_f32_16x16x32_bf16(af[mt], bfr[nt], acc[mt][nt], 0, 0, 0);
  }
#pragma unroll
  for (int nt = 0; nt < 4; ++nt) {
    const int col = g0 + wn * 64 + nt * 16 + l15;
    const float bias = bc[col];
#pragma unroll
    for (int mt = 0; mt < 4; ++mt) {
#pragma unroll
      for (int i = 0; i < 4; ++i) {
        const int row = r0 + wm * 64 + mt * 16 + quad * 4 + i;
        gB[(size_t)row * H5 + col] = acc[mt][nt][i] + bias;
      }
    }
  }
}

// ---------------- one LSTM timestep, both directions ----------------
__global__ __launch_bounds__(128)
void k_step(const float* __restrict__ Xf, const float* __restrict__ Xb,
            const float* __restrict__ Whf, const float* __restrict__ Whb,
            const float* __restrict__ bf, const float* __restrict__ bb,
            const int* __restrict__ len,
            float* __restrict__ hbuf, float* __restrict__ cbuf,
            float* __restrict__ hs, float* __restrict__ cs, int t)
{
  const int dir = blockIdx.y;
  const int jt = blockIdx.x;
  const int tid = threadIdx.x;
  const int b = tid & 15, j_loc = tid >> 4;
  const float* Wh = dir ? Whb : Whf;
  const float* bias = dir ? bb : bf;
  const float* X = dir ? Xb : Xf;
  const int pp = t & 1;
  const float* hp = hbuf + dir * 16384 + pp * 8192;
  const float* cp = cbuf + dir * 16384 + pp * 8192;
  float* hn = hbuf + dir * 16384 + (pp ^ 1) * 8192;
  float* cn = cbuf + dir * 16384 + (pp ^ 1) * 8192;
  __shared__ __align__(16) float hl[16 * 520];
  for (int i = tid; i < 8192; i += 128)
    hl[(i >> 9) * 520 + (i & 511)] = hp[i];
  __syncthreads();
  const int j = jt * 8 + j_loc;
  float acc0 = 0.f, acc1 = 0.f, acc2 = 0.f, acc3 = 0.f;
  const float4* h4 = (const float4*)(hl + b * 520);
  const float* w0 = Wh + (size_t)(0 * 512 + j) * 512;
  const float* w1 = Wh + (size_t)(1 * 512 + j) * 512;
  const float* w2 = Wh + (size_t)(2 * 512 + j) * 512;
  const float* w3 = Wh + (size_t)(3 * 512 + j) * 512;
  for (int w = 0; w < 128; ++w) {
    const float4 hv = h4[w];
    float4 a = *(const float4*)(w0 + w * 4);
    acc0 += hv.x * a.x + hv.y * a.y + hv.z * a.z + hv.w * a.w;
    a = *(const float4*)(w1 + w * 4);
    acc1 += hv.x * a.x + hv.y * a.y + hv.z * a.z + hv.w * a.w;
    a = *(const float4*)(w2 + w * 4);
    acc2 += hv.x * a.x + hv.y * a.y + hv.z * a.z + hv.w * a.w;
    a = *(const float4*)(w3 + w * 4);
    acc3 += hv.x * a.x + hv.y * a.y + hv.z * a.z + hv.w * a.w;
  }
  const int Lb = len[b];
  int xidx = t;
  if (dir) xidx = (t < Lb) ? (Lb - 1 - t) : t;
  const float* xr = X + (size_t)(b * SL + xidx) * 2048;
  const float gi = acc0 + xr[j] + bias[j];
  const float gf = acc1 + xr[512 + j] + bias[512 + j];
  const float gg = acc2 + xr[1024 + j] + bias[1024 + j];
  const float go = acc3 + xr[1536 + j] + bias[1536 + j];
  const float cprev = cp[b * 512 + j];
  const float cnew = sigf(gf) * cprev + sigf(gi) * tanhf(gg);
  const float hnew = sigf(go) * tanhf(cnew);
  hn[b * 512 + j] = hnew;
  cn[b * 512 + j] = cnew;
  const int pos = dir ? xidx : t;
  const int col = dir ? (512 + j) : j;
  hs[(size_t)(b * SL + pos) * 1024 + col] = hnew;
  cs[(size_t)(b * SL + pos) * 1024 + col] = cnew;
}

// ---------------- tree structure (argmax splits) + depth/link lists ----------------
__global__ __launch_bounds__(256)
void k_tree(const float* __restrict__ E1, const float* __restrict__ Wr1,
            const float* __restrict__ Wr2, const int* __restrict__ len,
            int* __restrict__ meta)
{
  const int b = blockIdx.x;
  const int tid = threadIdx.x;
  __shared__ float e[32 * 257];
  __shared__ float w1p[256];
  __shared__ float w2s[256];
  __shared__ float sc[32];
  __shared__ float red[32 * 8];
  __shared__ int stk[40 * 3];
  __shared__ int ctrl[8];
  for (int i = tid; i < 32 * 256; i += 256)
    e[(i >> 8) * 257 + (i & 255)] = E1[(size_t)(b * SL + (i >> 8)) * 256 + (i & 255)];
  w1p[tid] = Wr1[tid * 513 + 512];
  w2s[tid] = Wr2[tid];
  int* own = meta;
  int* lt = meta + 512;
  int* li = meta + 1024;
  int* rt = meta + 1536;
  int* ri = meta + 2048;
  int* dep = meta + 2560;
  int* nn = meta + 3072;
  int* dcnt = meta + 3088;
  int* lcnt = meta + 3120;
  int* dlist = meta + 3152;
  int* llist = meta + 19536;
  if (tid < 32) dep[b * 32 + tid] = -1;
  if (tid == 0) {
    ctrl[0] = 1;
    ctrl[1] = 1;
    stk[0] = 0; stk[1] = len[b]; stk[2] = 0;
  }
  const int t_ = tid & 31, jg = tid >> 5;
  while (true) {
    __syncthreads();
    if (tid == 0) {
      int sp = ctrl[0];
      if (sp == 0) ctrl[4] = -1;
      else {
        sp--;
        ctrl[0] = sp;
        ctrl[2] = stk[sp * 3];
        ctrl[3] = stk[sp * 3 + 1];
        ctrl[4] = stk[sp * 3 + 2];
      }
    }
    __syncthreads();
    const int nid = ctrl[4];
    if (nid < 0) break;
    const int s = ctrl[2], eN = ctrl[3], l = eN - s;
    float part = 0.0f;
    if (t_ < l) {
      const float pos = 2.0f * (float)t_ / (float)l - 1.0f;
      const float* er = e + (s + t_) * 257;
      for (int q = jg * 32; q < jg * 32 + 32; ++q) {
        const float v = er[q] + pos * w1p[q];
        part += fmaxf(v, 0.0f) * w2s[q];
      }
    }
    red[t_ * 8 + jg] = part;
    __syncthreads();
    if (jg == 0 && t_ < l) {
      float su = 0.0f;
      for (int q = 0; q < 8; ++q) su += red[t_ * 8 + q];
      sc[t_] = su;
    }
    __syncthreads();
    if (tid == 0) {
      int k = 0;
      float best = sc[0];
      for (int q = 1; q < l; ++q)
        if (sc[q] > best) { best = sc[q]; k = q; }
      const int m = b * 32 + nid;
      own[m] = s + k;
      int nn_ = ctrl[1], sp = ctrl[0];
      if (k == 0) { lt[m] = 0; li[m] = 0; }
      else if (k == 1) { lt[m] = 1; li[m] = s; }
      else {
        const int id = nn_++;
        lt[m] = 2; li[m] = id;
        stk[sp * 3] = s; stk[sp * 3 + 1] = s + k; stk[sp * 3 + 2] = id; sp++;
      }
      const int rl = l - k - 1;
      if (rl == 0) { rt[m] = 0; ri[m] = 0; }
      else if (rl == 1) { rt[m] = 1; ri[m] = s + k + 1; }
      else {
        const int id = nn_++;
        rt[m] = 2; ri[m] = id;
        stk[sp * 3] = s + k + 1; stk[sp * 3 + 1] = eN; stk[sp * 3 + 2] = id; sp++;
      }
      ctrl[0] = sp; ctrl[1] = nn_;
    }
  }
  __syncthreads();
  if (tid == 0) {
    const int n_ = ctrl[1];
    nn[b] = n_;
    for (int i = n_ - 1; i >= 0; --i) {
      const int m = b * 32 + i;
      int d = 1;
      if (lt[m] == 2) d = max(d, dep[b * 32 + li[m]] + 1);
      if (rt[m] == 2) d = max(d, dep[b * 32 + ri[m]] + 1);
      dep[m] = d;
    }
    for (int i = 0; i < n_; ++i) {
      const int m = b * 32 + i;
      const int r = dep[m];
      const int idx = atomicAdd(&dcnt[r], 1);
      dlist[r * 512 + idx] = m;
      if (lt[m] == 2 || rt[m] == 2) {
        const int lx = atomicAdd(&lcnt[r], 1);
        llist[r * 512 + lx] = m;
      }
    }
  }
}

// ---------------- build U (bf16) = [hl_leaf|0 , hr_leaf|0 , hx] per node ----------------
__global__ __launch_bounds__(256)
void k_ubuild(const float* __restrict__ hs, const int* __restrict__ meta,
              unsigned short* __restrict__ U)
{
  const int id = blockIdx.x, b = blockIdx.y;
  const int tid = threadIdx.x;
  const int* own = meta;
  const int* lt = meta + 512;
  const int* li = meta + 1024;
  const int* rt = meta + 1536;
  const int* ri = meta + 2048;
  const int* nn = meta + 3072;
  const int m = b * 32 + id;
  unsigned short* u = U + (size_t)m * K3;
  if (id >= nn[b]) {
    for (int i = tid; i < K3; i += 256) u[i] = 0;
    return;
  }
  const float* hl = (lt[m] == 1) ? hs + (size_t)(b * 32 + li[m]) * 1024 : nullptr;
  const float* hr = (rt[m] == 1) ? hs + (size_t)(b * 32 + ri[m]) * 1024 : nullptr;
  const float* hx = hs + (size_t)(b * 32 + own[m]) * 1024;
  for (int i = tid; i < 1024; i += 256) {
    u[i] = hl ? f2bf(hl[i]) : 0;
    u[1024 + i] = hr ? f2bf(hr[i]) : 0;
    u[2048 + i] = f2bf(hx[i]);
  }
}

// ---------------- per-depth link GEMM (bf16 MFMA) ----------------
// gB[node,g] += sum_{k<1024} Wc[g,k]*hl_int[k] + sum_{k in [1024,2048)} Wc[g,k]*hr_int[k-1024]
// M = lcnt[r] (compacted, pad 64), N-tile 32 -> grid (160, 8), block 256 (4 waves)
__global__ __launch_bounds__(256)
void k_linkgemm(const float* __restrict__ Wc, const int* __restrict__ meta,
                const unsigned short* __restrict__ nodehb, float* __restrict__ gB, int r)
{
  const int* lt = meta + 512;
  const int* li = meta + 1024;
  const int* rt = meta + 1536;
  const int* ri = meta + 2048;
  const int* lcnt = meta + 3120;
  const int* llist = meta + 19536;
  const int cnt = lcnt[r];
  const int m0 = blockIdx.y * 64;
  if (m0 >= cnt) return;
  __shared__ __align__(16) unsigned short As[64 * 40];
  __shared__ __align__(16) unsigned short Bs[32 * 40];
  __shared__ int sofs[2][64];
  __shared__ int snode[64];
  const int tid = threadIdx.x;
  if (tid < 64) {
    int ofs_l = -1, ofs_r = -1, node = -1;
    const int m = m0 + tid;
    if (m < cnt) {
      node = llist[r * 512 + m];
      const int base = node & ~31;
      if (lt[node] == 2) ofs_l = (base + li[node]) * 1024;
      if (rt[node] == 2) ofs_r = (base + ri[node]) * 1024;
    }
    snode[tid] = node;
    sofs[0][tid] = ofs_l;
    sofs[1][tid] = ofs_r;
  }
  __syncthreads();
  const int g0 = blockIdx.x * 32;
  const int wave = tid >> 6, lane = tid & 63;
  const int l15 = lane & 15, quad = lane >> 4;
  const int a_row = tid >> 2, a_q = tid & 3;
  floatx4 acc[2];
  acc[0] = (floatx4){0.f, 0.f, 0.f, 0.f};
  acc[1] = (floatx4){0.f, 0.f, 0.f, 0.f};
  const uint4 z4 = make_uint4(0, 0, 0, 0);

  for (int kt = 0; kt < 2048; kt += 32) {
    __syncthreads();
    // stage A: 64 rows x 32 k bf16, gathered from nodehb
    {
      const int kk = kt + a_q * 8;
      const int side = kk >> 10;
      const int kl = kk & 1023;
      const int ofs = sofs[side][a_row];
      *(uint4*)&As[a_row * 40 + a_q * 8] =
          (ofs >= 0) ? *(const uint4*)&nodehb[(size_t)ofs + kl] : z4;
    }
    // stage B: 32 gates x 32 k, f32 -> bf16 on the fly
    if (tid < 128) {
      const int row = tid >> 2, q = tid & 3;
      const float4 v0 = *(const float4*)&Wc[(size_t)(g0 + row) * K3 + kt + q * 8];
      const float4 v1 = *(const float4*)&Wc[(size_t)(g0 + row) * K3 + kt + q * 8 + 4];
      ushort4 o0, o1;
      o0.x = f2bf(v0.x); o0.y = f2bf(v0.y); o0.z = f2bf(v0.z); o0.w = f2bf(v0.w);
      o1.x = f2bf(v1.x); o1.y = f2bf(v1.y); o1.z = f2bf(v1.z); o1.w = f2bf(v1.w);
      *(ushort4*)&Bs[row * 40 + q * 8] = o0;
      *(ushort4*)&Bs[row * 40 + q * 8 + 4] = o1;
    }
    __syncthreads();
    const short8 a = *(const short8*)&As[(wave * 16 + l15) * 40 + quad * 8];
    const short8 b0 = *(const short8*)&Bs[(l15)*40 + quad * 8];
    const short8 b1 = *(const short8*)&Bs[(16 + l15) * 40 + quad * 8];
    acc[0] = __builtin_amdgcn_mfma_f32_16x16x32_bf16(a, b0, acc[0], 0, 0, 0);
    acc[1] = __builtin_amdgcn_mfma_f32_16x16x32_bf16(a, b1, acc[1], 0, 0, 0);
  }
  // epilogue: D[row=quad*4+i][col=l15]; row -> node, col -> gate
#pragma unroll
  for (int nt = 0; nt < 2; ++nt) {
    const int col = g0 + nt * 16 + l15;
#pragma unroll
    for (int i = 0; i < 4; ++i) {
      const int rowm = wave * 16 + quad * 4 + i;
      if (m0 + rowm < cnt) {
        const int node = snode[rowm];
        gB[(size_t)node * H5 + col] += acc[nt][i];
      }
    }
  }
}

// ---------------- per-depth gating ----------------
__global__ void k_gate(const float* __restrict__ gB, const float* __restrict__ cs,
                       const int* __restrict__ meta, float* __restrict__ nodeh,
                       float* __restrict__ nodec, unsigned short* __restrict__ nodehb, int r)
{
  const int* lt = meta + 512;
  const int* li = meta + 1024;
  const int* rt = meta + 1536;
  const int* ri = meta + 2048;
  const int* dcnt = meta + 3088;
  const int* dlist = meta + 3152;
  const int cnt = dcnt[r];
  const int m = blockIdx.x;
  if (m >= cnt) return;
  const int node = dlist[r * 512 + m];
  const int base = node & ~31;
  const int ltv = lt[node], rtv = rt[node];
  const float* clp = (ltv == 2) ? &nodec[(size_t)(base + li[node]) * 1024]
                   : (ltv == 1) ? &cs[(size_t)(base + li[node]) * 1024] : nullptr;
  const float* crp = (rtv == 2) ? &nodec[(size_t)(base + ri[node]) * 1024]
                   : (rtv == 1) ? &cs[(size_t)(base + ri[node]) * 1024] : nullptr;
  const float* g = &gB[(size_t)node * H5];
  for (int j = threadIdx.x; j < 1024; j += 256) {
    const float gi = g[j];
    const float gfl = g[1024 + j];
    const float gfr = g[2048 + j];
    const float gu = g[3072 + j];
    const float go = g[4096 + j];
    const float cl = clp ? clp[j] : 0.0f;
    const float cr = crp ? crp[j] : 0.0f;
    const float c = sigf(gfl) * cl + sigf(gfr) * cr + sigf(gi) * tanhf(gu);
    const float h = sigf(go) * tanhf(c);
    nodeh[(size_t)node * 1024 + j] = h;
    nodec[(size_t)node * 1024 + j] = c;
    nodehb[(size_t)node * 1024 + j] = f2bf(h);
  }
}

// ---------------- gather roots ----------------
__global__ void k_out(const float* __restrict__ nodeh, const float* __restrict__ nodec,
                      float* __restrict__ out)
{
  const int b = blockIdx.x;
  const int tid = threadIdx.x;
  for (int i = tid; i < 1024; i += 256) {
    out[b * 1024 + i] = nodeh[(size_t)(b * 32) * 1024 + i];
    out[16384 + b * 1024 + i] = nodec[(size_t)(b * 32) * 1024 + i];
  }
}

extern "C" void kernel_launch(void* const* d_in, const int* in_sizes, int n_in,
                              void* d_out, int out_size, void* d_ws, size_t ws_size,
                              hipStream_t stream) {
  const float* emb = (const float*)d_in[0];
  const int* len = (const int*)d_in[1];
  const float* Wihf = (const float*)d_in[2];
  const float* Whhf = (const float*)d_in[3];
  const float* bf = (const float*)d_in[4];
  const float* Wihb = (const float*)d_in[5];
  const float* Whhb = (const float*)d_in[6];
  const float* bb = (const float*)d_in[7];
  const float* Wr1 = (const float*)d_in[8];
  const float* Wr2 = (const float*)d_in[9];
  const float* Wc = (const float*)d_in[10];
  const float* bc = (const float*)d_in[11];
  float* out = (float*)d_out;

  float* ws = (float*)d_ws;
  float* Xf = ws;                                       // 1048576 f
  float* Xb = Xf + 1048576;                             // 1048576 f
  float* hs = Xb + 1048576;                             // 524288 f
  float* cs = hs + 524288;                              // 524288 f
  float* hbuf = cs + 524288;                            // 32768 f
  float* cbuf = hbuf + 32768;                           // 32768 f
  float* E1 = cbuf + 32768;                             // 131072 f
  unsigned short* U = (unsigned short*)(E1 + 131072);   // 1572864 us = 786432 f
  float* gB = (float*)U + 786432;                       // 2621440 f
  float* nodeh = gB + 2621440;                          // 524288 f
  float* nodec = nodeh + 524288;                        // 524288 f
  unsigned short* nodehb = (unsigned short*)(nodec + 524288);  // 524288 us = 262144 f
  int* meta = (int*)((float*)nodehb + 262144);          // ~36K ints

  // zero LSTM ping-pong state + per-depth counters
  k_zero<<<256, 256, 0, stream>>>(hbuf, 65536);
  k_zero<<<1, 64, 0, stream>>>((float*)(meta + 3088), 64);
  // input projections + rank projection
  k_gemm<<<dim3(32, 8), 256, 0, stream>>>(emb, 512, Wihf, 512, Xf, 2048, 512);
  k_gemm<<<dim3(32, 8), 256, 0, stream>>>(emb, 512, Wihb, 512, Xb, 2048, 512);
  k_gemm<<<dim3(4, 8), 256, 0, stream>>>(emb, 512, Wr1, 513, E1, 256, 512);
  // recurrent scan
  for (int t = 0; t < SL; ++t)
    k_step<<<dim3(64, 2), 128, 0, stream>>>(Xf, Xb, Whhf, Whhb, bf, bb, len,
                                            hbuf, cbuf, hs, cs, t);
  // tree structure + depth/link lists
  k_tree<<<16, 256, 0, stream>>>(E1, Wr1, Wr2, len, meta);
  // precomputable part of every compose (own + leaf children) via bf16 MFMA
  k_ubuild<<<dim3(32, 16), 256, 0, stream>>>(hs, meta, U);
  k_mfma_gemm<<<dim3(40, 4), 256, 0, stream>>>(U, Wc, bc, gB);
  // depth-ordered compose rounds (linkgemm early-exits when no internal-child links)
  for (int r = 1; r <= 31; ++r) {
    k_linkgemm<<<dim3(160, 8), 256, 0, stream>>>(Wc, meta, nodehb, gB, r);
    k_gate<<<512, 256, 0, stream>>>(gB, cs, meta, nodeh, nodec, nodehb, r);
  }
  k_out<<<16, 256, 0, stream>>>(nodeh, nodec, out);
}

// Round 4
// 902.723 us; speedup vs baseline: 3.0139x; 1.6783x over previous
//
#include <hip/hip_runtime.h>
#include <math.h>

#define NB 16
#define SL 32
#define H5 5120
#define K3 3072

typedef __attribute__((ext_vector_type(8))) short short8;
typedef __attribute__((ext_vector_type(4))) float floatx4;

__device__ __forceinline__ float sigf(float x) { return 1.0f / (1.0f + expf(-x)); }

__device__ __forceinline__ unsigned short f2bf(float x) {
  union { float f; unsigned int u; } v;
  v.f = x;
  unsigned int r = v.u + 0x7FFFu + ((v.u >> 16) & 1u);
  return (unsigned short)(r >> 16);
}

// meta layout (ints):
//  own 0, lt 512, li 1024, rt 1536, ri 2048, dep 2560, nn 3072(16),
//  dcnt 3088(32), lcnt 3120(32), dlist 3152(32*512), llist 19536(32*512)

// ---------------- zero ----------------
__global__ void k_zero(float* __restrict__ p, int n) {
  int i = blockIdx.x * blockDim.x + threadIdx.x;
  if (i < n) p[i] = 0.0f;
}

// ---------------- batch f32 -> bf16 conversion (6 segments) ----------------
__global__ void k_conv6(const float* s0, unsigned short* d0, int n0,
                        const float* s1, unsigned short* d1, int n1,
                        const float* s2, unsigned short* d2, int n2,
                        const float* s3, unsigned short* d3, int n3,
                        const float* s4, unsigned short* d4, int n4,
                        const float* s5, unsigned short* d5, int n5)
{
  const float* s; unsigned short* d; int n;
  switch (blockIdx.y) {
    case 0: s = s0; d = d0; n = n0; break;
    case 1: s = s1; d = d1; n = n1; break;
    case 2: s = s2; d = d2; n = n2; break;
    case 3: s = s3; d = d3; n = n3; break;
    case 4: s = s4; d = d4; n = n4; break;
    default: s = s5; d = d5; n = n5; break;
  }
  const int nf4 = n >> 2;
  for (int i = blockIdx.x * blockDim.x + threadIdx.x; i < nf4; i += gridDim.x * blockDim.x) {
    const float4 v = *(const float4*)&s[i * 4];
    ushort4 o;
    o.x = f2bf(v.x); o.y = f2bf(v.y); o.z = f2bf(v.z); o.w = f2bf(v.w);
    *(ushort4*)&d[i * 4] = o;
  }
}

// ---- generic f32 GEMM (only used for E1): out[r,g] = sum_k A[r,k]*W[g,k]
__global__ __launch_bounds__(256)
void k_gemm(const float* __restrict__ A, int lda,
            const float* __restrict__ W, int ldw,
            float* __restrict__ out, int N, int K)
{
  __shared__ __align__(16) float sm[2 * 16 * 68];
  float* As = sm;
  float* Ws = sm + 16 * 68;
  const int tid = threadIdx.x;
  const int tx = tid & 15, ty = tid >> 4;
  const int g0 = blockIdx.x * 64, r0 = blockIdx.y * 64;
  float acc[4][4];
#pragma unroll
  for (int i = 0; i < 4; ++i)
#pragma unroll
    for (int j = 0; j < 4; ++j) acc[i][j] = 0.0f;
  const int ks = tid & 15, rr = tid >> 4;
  for (int kt = 0; kt < K; kt += 16) {
#pragma unroll
    for (int rep = 0; rep < 4; ++rep) {
      As[ks * 68 + rep * 16 + rr] = A[(size_t)(r0 + rep * 16 + rr) * lda + kt + ks];
      Ws[ks * 68 + rep * 16 + rr] = W[(size_t)(g0 + rep * 16 + rr) * ldw + kt + ks];
    }
    __syncthreads();
#pragma unroll
    for (int k = 0; k < 16; ++k) {
      const float4 a4 = *(const float4*)&As[k * 68 + ty * 4];
      const float4 w4 = *(const float4*)&Ws[k * 68 + tx * 4];
      const float av[4] = {a4.x, a4.y, a4.z, a4.w};
      const float wv[4] = {w4.x, w4.y, w4.z, w4.w};
#pragma unroll
      for (int i = 0; i < 4; ++i)
#pragma unroll
        for (int j = 0; j < 4; ++j) acc[i][j] += av[i] * wv[j];
    }
    __syncthreads();
  }
#pragma unroll
  for (int i = 0; i < 4; ++i) {
    const int r = r0 + ty * 4 + i;
    float4 o;
    o.x = acc[i][0]; o.y = acc[i][1]; o.z = acc[i][2]; o.w = acc[i][3];
    *(float4*)&out[(size_t)r * N + g0 + tx * 4] = o;
  }
}

// ---------------- input projection MFMA: X = embB @ WihB^T ----------------
// M=512 tokens, N=2048, K=512. grid (16, 4, 2dir), block 256 (2x2 waves, 64x64 each)
__global__ __launch_bounds__(256)
void k_xproj(const unsigned short* __restrict__ embB,
             const unsigned short* __restrict__ WfB, const unsigned short* __restrict__ WbB,
             float* __restrict__ Xf, float* __restrict__ Xb)
{
  const unsigned short* B = blockIdx.z ? WbB : WfB;
  float* out = blockIdx.z ? Xb : Xf;
  __shared__ __align__(16) unsigned short As[128 * 40];
  __shared__ __align__(16) unsigned short Bs[128 * 40];
  const int tid = threadIdx.x;
  const int g0 = blockIdx.x * 128;
  const int r0 = blockIdx.y * 128;
  const int wave = tid >> 6, lane = tid & 63;
  const int wm = wave >> 1, wn = wave & 1;
  const int l15 = lane & 15, quad = lane >> 4;
  floatx4 acc[4][4];
#pragma unroll
  for (int mt = 0; mt < 4; ++mt)
#pragma unroll
    for (int nt = 0; nt < 4; ++nt) acc[mt][nt] = (floatx4){0.f, 0.f, 0.f, 0.f};
  for (int kt = 0; kt < 512; kt += 32) {
    __syncthreads();
#pragma unroll
    for (int p = 0; p < 2; ++p) {
      const int i = tid + p * 256;
      const int row = i >> 2, q = i & 3;
      *(uint4*)&As[row * 40 + q * 8] = *(const uint4*)&embB[(size_t)(r0 + row) * 512 + kt + q * 8];
      *(uint4*)&Bs[row * 40 + q * 8] = *(const uint4*)&B[(size_t)(g0 + row) * 512 + kt + q * 8];
    }
    __syncthreads();
    short8 af[4], bfr[4];
#pragma unroll
    for (int mt = 0; mt < 4; ++mt)
      af[mt] = *(const short8*)&As[(wm * 64 + mt * 16 + l15) * 40 + quad * 8];
#pragma unroll
    for (int nt = 0; nt < 4; ++nt)
      bfr[nt] = *(const short8*)&Bs[(wn * 64 + nt * 16 + l15) * 40 + quad * 8];
#pragma unroll
    for (int mt = 0; mt < 4; ++mt)
#pragma unroll
      for (int nt = 0; nt < 4; ++nt)
        acc[mt][nt] = __builtin_amdgcn_mfma_f32_16x16x32_bf16(af[mt], bfr[nt], acc[mt][nt], 0, 0, 0);
  }
#pragma unroll
  for (int nt = 0; nt < 4; ++nt) {
    const int col = g0 + wn * 64 + nt * 16 + l15;
#pragma unroll
    for (int mt = 0; mt < 4; ++mt)
#pragma unroll
      for (int i = 0; i < 4; ++i) {
        const int row = r0 + wm * 64 + mt * 16 + quad * 4 + i;
        out[(size_t)row * 2048 + col] = acc[mt][nt][i];
      }
  }
}

// ---------------- big compose GEMM: gB[r,g] = bc[g] + U @ WcB^T ----------------
// M=512, N=5120, K=3072. 1-D grid 320 = 4 mtiles(128) x 80 ntiles(64); bid = m*80+n
// (80%8==0 -> all m-blocks of an n-tile land on the same XCD: B-slice stays L2-resident)
__global__ __launch_bounds__(256)
void k_mfma_gemm(const unsigned short* __restrict__ U, const unsigned short* __restrict__ WcB,
                 const float* __restrict__ bc, float* __restrict__ gB)
{
  __shared__ __align__(16) unsigned short As[128 * 40];
  __shared__ __align__(16) unsigned short Bs[64 * 40];
  const int bid = blockIdx.x;
  const int r0 = (bid / 80) * 128;
  const int g0 = (bid % 80) * 64;
  const int tid = threadIdx.x;
  const int wave = tid >> 6, lane = tid & 63;
  const int wm = wave >> 1, wn = wave & 1;   // wm: 2x64 rows, wn: 2x32 cols
  const int l15 = lane & 15, quad = lane >> 4;
  floatx4 acc[4][2];
#pragma unroll
  for (int mf = 0; mf < 4; ++mf)
#pragma unroll
    for (int nt = 0; nt < 2; ++nt) acc[mf][nt] = (floatx4){0.f, 0.f, 0.f, 0.f};
  const int a_row = tid >> 2, a_q = tid & 3;
  for (int kt = 0; kt < K3; kt += 32) {
    __syncthreads();
#pragma unroll
    for (int p = 0; p < 2; ++p) {
      const int i = tid + p * 256;
      const int row = i >> 2, q = i & 3;
      *(uint4*)&As[row * 40 + q * 8] = *(const uint4*)&U[(size_t)(r0 + row) * K3 + kt + q * 8];
    }
    *(uint4*)&Bs[a_row * 40 + a_q * 8] = *(const uint4*)&WcB[(size_t)(g0 + a_row) * K3 + kt + a_q * 8];
    __syncthreads();
    short8 af[4], bfr[2];
#pragma unroll
    for (int mf = 0; mf < 4; ++mf)
      af[mf] = *(const short8*)&As[(wm * 64 + mf * 16 + l15) * 40 + quad * 8];
#pragma unroll
    for (int nt = 0; nt < 2; ++nt)
      bfr[nt] = *(const short8*)&Bs[(wn * 32 + nt * 16 + l15) * 40 + quad * 8];
#pragma unroll
    for (int mf = 0; mf < 4; ++mf)
#pragma unroll
      for (int nt = 0; nt < 2; ++nt)
        acc[mf][nt] = __builtin_amdgcn_mfma_f32_16x16x32_bf16(af[mf], bfr[nt], acc[mf][nt], 0, 0, 0);
  }
#pragma unroll
  for (int nt = 0; nt < 2; ++nt) {
    const int col = g0 + wn * 32 + nt * 16 + l15;
    const float bias = bc[col];
#pragma unroll
    for (int mf = 0; mf < 4; ++mf)
#pragma unroll
      for (int i = 0; i < 4; ++i) {
        const int row = r0 + wm * 64 + mf * 16 + quad * 4 + i;
        gB[(size_t)row * H5 + col] = acc[mf][nt][i] + bias;
      }
  }
}

// ---------------- one LSTM timestep, MFMA version ----------------
// grid (32 hj-tiles, 2 dir), block 256 = 4 waves; wave w computes gate-quarter w
// for 16 hj columns x all 16 batches. h-state is bf16 (hbB), c-state f32 (cbuf).
__global__ __launch_bounds__(256)
void k_stepm(const float* __restrict__ Xf, const float* __restrict__ Xb,
             const unsigned short* __restrict__ WhfB, const unsigned short* __restrict__ WhbB,
             const float* __restrict__ bf, const float* __restrict__ bb,
             const int* __restrict__ len,
             unsigned short* __restrict__ hbB, float* __restrict__ cbuf,
             float* __restrict__ hs, float* __restrict__ cs, int t)
{
  const int dir = blockIdx.y;
  const int hjt = blockIdx.x;
  const int tid = threadIdx.x;
  const int wave = tid >> 6, lane = tid & 63;
  const int l15 = lane & 15, quad = lane >> 4;
  const unsigned short* Wh = dir ? WhbB : WhfB;
  const float* bias = dir ? bb : bf;
  const float* X = dir ? Xb : Xf;
  const int pp = t & 1;
  const unsigned short* hp = hbB + (size_t)(dir * 2 + pp) * 8192;
  unsigned short* hn = hbB + (size_t)(dir * 2 + (pp ^ 1)) * 8192;
  const float* cp = cbuf + (size_t)(dir * 2 + pp) * 8192;
  float* cn = cbuf + (size_t)(dir * 2 + (pp ^ 1)) * 8192;

  __shared__ float sg[4 * 16 * 17];  // [gate][b][hj] padded
  floatx4 acc = (floatx4){0.f, 0.f, 0.f, 0.f};
  const int jg = wave * 512 + hjt * 16 + l15;  // global gate row
  for (int kt = 0; kt < 512; kt += 32) {
    const short8 a = *(const short8*)&hp[(size_t)l15 * 512 + kt + quad * 8];
    const short8 b = *(const short8*)&Wh[(size_t)jg * 512 + kt + quad * 8];
    acc = __builtin_amdgcn_mfma_f32_16x16x32_bf16(a, b, acc, 0, 0, 0);
  }
  // D: col(l15) = hj within tile, row(quad*4+i) = batch
#pragma unroll
  for (int i = 0; i < 4; ++i)
    sg[wave * 272 + (quad * 4 + i) * 17 + l15] = acc[i];
  __syncthreads();
  // gating: 256 threads = 16 b x 16 j
  const int b = tid >> 4, j = tid & 15;
  const int hj = hjt * 16 + j;
  const int Lb = len[b];
  int xidx = t;
  if (dir) xidx = (t < Lb) ? (Lb - 1 - t) : t;
  const float* xr = X + (size_t)(b * SL + xidx) * 2048;
  const float gi = sg[0 * 272 + b * 17 + j] + xr[hj] + bias[hj];
  const float gf = sg[1 * 272 + b * 17 + j] + xr[512 + hj] + bias[512 + hj];
  const float gg = sg[2 * 272 + b * 17 + j] + xr[1024 + hj] + bias[1024 + hj];
  const float go = sg[3 * 272 + b * 17 + j] + xr[1536 + hj] + bias[1536 + hj];
  const float cprev = cp[b * 512 + hj];
  const float cnew = sigf(gf) * cprev + sigf(gi) * tanhf(gg);
  const float hnew = sigf(go) * tanhf(cnew);
  cn[b * 512 + hj] = cnew;
  hn[b * 512 + hj] = f2bf(hnew);
  const int pos = dir ? xidx : t;
  const int col = dir ? (512 + hj) : hj;
  hs[(size_t)(b * SL + pos) * 1024 + col] = hnew;
  cs[(size_t)(b * SL + pos) * 1024 + col] = cnew;
}

// ---------------- tree structure (argmax splits) + depth/link lists ----------------
__global__ __launch_bounds__(256)
void k_tree(const float* __restrict__ E1, const float* __restrict__ Wr1,
            const float* __restrict__ Wr2, const int* __restrict__ len,
            int* __restrict__ meta)
{
  const int b = blockIdx.x;
  const int tid = threadIdx.x;
  __shared__ float e[32 * 257];
  __shared__ float w1p[256];
  __shared__ float w2s[256];
  __shared__ float sc[32];
  __shared__ float red[32 * 8];
  __shared__ int stk[40 * 3];
  __shared__ int ctrl[8];
  for (int i = tid; i < 32 * 256; i += 256)
    e[(i >> 8) * 257 + (i & 255)] = E1[(size_t)(b * SL + (i >> 8)) * 256 + (i & 255)];
  w1p[tid] = Wr1[tid * 513 + 512];
  w2s[tid] = Wr2[tid];
  int* own = meta;
  int* lt = meta + 512;
  int* li = meta + 1024;
  int* rt = meta + 1536;
  int* ri = meta + 2048;
  int* dep = meta + 2560;
  int* nn = meta + 3072;
  int* dcnt = meta + 3088;
  int* lcnt = meta + 3120;
  int* dlist = meta + 3152;
  int* llist = meta + 19536;
  if (tid < 32) dep[b * 32 + tid] = -1;
  if (tid == 0) {
    ctrl[0] = 1;
    ctrl[1] = 1;
    stk[0] = 0; stk[1] = len[b]; stk[2] = 0;
  }
  const int t_ = tid & 31, jg = tid >> 5;
  while (true) {
    __syncthreads();
    if (tid == 0) {
      int sp = ctrl[0];
      if (sp == 0) ctrl[4] = -1;
      else {
        sp--;
        ctrl[0] = sp;
        ctrl[2] = stk[sp * 3];
        ctrl[3] = stk[sp * 3 + 1];
        ctrl[4] = stk[sp * 3 + 2];
      }
    }
    __syncthreads();
    const int nid = ctrl[4];
    if (nid < 0) break;
    const int s = ctrl[2], eN = ctrl[3], l = eN - s;
    float part = 0.0f;
    if (t_ < l) {
      const float pos = 2.0f * (float)t_ / (float)l - 1.0f;
      const float* er = e + (s + t_) * 257;
      for (int q = jg * 32; q < jg * 32 + 32; ++q) {
        const float v = er[q] + pos * w1p[q];
        part += fmaxf(v, 0.0f) * w2s[q];
      }
    }
    red[t_ * 8 + jg] = part;
    __syncthreads();
    if (jg == 0 && t_ < l) {
      float su = 0.0f;
      for (int q = 0; q < 8; ++q) su += red[t_ * 8 + q];
      sc[t_] = su;
    }
    __syncthreads();
    if (tid == 0) {
      int k = 0;
      float best = sc[0];
      for (int q = 1; q < l; ++q)
        if (sc[q] > best) { best = sc[q]; k = q; }
      const int m = b * 32 + nid;
      own[m] = s + k;
      int nn_ = ctrl[1], sp = ctrl[0];
      if (k == 0) { lt[m] = 0; li[m] = 0; }
      else if (k == 1) { lt[m] = 1; li[m] = s; }
      else {
        const int id = nn_++;
        lt[m] = 2; li[m] = id;
        stk[sp * 3] = s; stk[sp * 3 + 1] = s + k; stk[sp * 3 + 2] = id; sp++;
      }
      const int rl = l - k - 1;
      if (rl == 0) { rt[m] = 0; ri[m] = 0; }
      else if (rl == 1) { rt[m] = 1; ri[m] = s + k + 1; }
      else {
        const int id = nn_++;
        rt[m] = 2; ri[m] = id;
        stk[sp * 3] = s + k + 1; stk[sp * 3 + 1] = eN; stk[sp * 3 + 2] = id; sp++;
      }
      ctrl[0] = sp; ctrl[1] = nn_;
    }
  }
  __syncthreads();
  if (tid == 0) {
    const int n_ = ctrl[1];
    nn[b] = n_;
    for (int i = n_ - 1; i >= 0; --i) {
      const int m = b * 32 + i;
      int d = 1;
      if (lt[m] == 2) d = max(d, dep[b * 32 + li[m]] + 1);
      if (rt[m] == 2) d = max(d, dep[b * 32 + ri[m]] + 1);
      dep[m] = d;
    }
    for (int i = 0; i < n_; ++i) {
      const int m = b * 32 + i;
      const int r = dep[m];
      const int idx = atomicAdd(&dcnt[r], 1);
      dlist[r * 512 + idx] = m;
      if (lt[m] == 2 || rt[m] == 2) {
        const int lx = atomicAdd(&lcnt[r], 1);
        llist[r * 512 + lx] = m;
      }
    }
  }
}

// ---------------- build U (bf16) = [hl_leaf|0 , hr_leaf|0 , hx] per node ----------------
__global__ __launch_bounds__(256)
void k_ubuild(const float* __restrict__ hs, const int* __restrict__ meta,
              unsigned short* __restrict__ U)
{
  const int id = blockIdx.x, b = blockIdx.y;
  const int tid = threadIdx.x;
  const int* own = meta;
  const int* lt = meta + 512;
  const int* li = meta + 1024;
  const int* rt = meta + 1536;
  const int* ri = meta + 2048;
  const int* nn = meta + 3072;
  const int m = b * 32 + id;
  unsigned short* u = U + (size_t)m * K3;
  if (id >= nn[b]) {
    for (int i = tid; i < K3; i += 256) u[i] = 0;
    return;
  }
  const float* hl = (lt[m] == 1) ? hs + (size_t)(b * 32 + li[m]) * 1024 : nullptr;
  const float* hr = (rt[m] == 1) ? hs + (size_t)(b * 32 + ri[m]) * 1024 : nullptr;
  const float* hx = hs + (size_t)(b * 32 + own[m]) * 1024;
  for (int i = tid; i < 1024; i += 256) {
    u[i] = hl ? f2bf(hl[i]) : 0;
    u[1024 + i] = hr ? f2bf(hr[i]) : 0;
    u[2048 + i] = f2bf(hx[i]);
  }
}

// ---------------- per-depth link GEMM (bf16 MFMA, bf16 WcB) ----------------
// gB[node,g] += WcB[g, 0:2048] . [hl_int | hr_int] (zeros for leaf sides)
// N-tile 64, M-chunks of 64 with stride-2 loop. grid (80, 2), block 256.
__global__ __launch_bounds__(256)
void k_linkgemm(const unsigned short* __restrict__ WcB, const int* __restrict__ meta,
                const unsigned short* __restrict__ nodehb, float* __restrict__ gB, int r)
{
  const int* lt = meta + 512;
  const int* li = meta + 1024;
  const int* rt = meta + 1536;
  const int* ri = meta + 2048;
  const int* lcnt = meta + 3120;
  const int* llist = meta + 19536;
  const int cnt = lcnt[r];
  if (cnt == 0) return;
  __shared__ __align__(16) unsigned short As[64 * 40];
  __shared__ __align__(16) unsigned short Bs[64 * 40];
  __shared__ int sofs[2][64];
  __shared__ int snode[64];
  const int tid = threadIdx.x;
  const int g0 = blockIdx.x * 64;
  const int wave = tid >> 6, lane = tid & 63;
  const int l15 = lane & 15, quad = lane >> 4;
  const int a_row = tid >> 2, a_q = tid & 3;
  const uint4 z4 = make_uint4(0, 0, 0, 0);

  for (int mt = blockIdx.y; mt * 64 < cnt; mt += 2) {
    const int m0 = mt * 64;
    __syncthreads();
    if (tid < 64) {
      int ofs_l = -1, ofs_r = -1, node = -1;
      const int m = m0 + tid;
      if (m < cnt) {
        node = llist[r * 512 + m];
        const int base = node & ~31;
        if (lt[node] == 2) ofs_l = (base + li[node]) * 1024;
        if (rt[node] == 2) ofs_r = (base + ri[node]) * 1024;
      }
      snode[tid] = node;
      sofs[0][tid] = ofs_l;
      sofs[1][tid] = ofs_r;
    }
    __syncthreads();
    floatx4 acc[4];
#pragma unroll
    for (int mf = 0; mf < 4; ++mf) acc[mf] = (floatx4){0.f, 0.f, 0.f, 0.f};
    for (int kt = 0; kt < 2048; kt += 32) {
      __syncthreads();
      {
        const int kk = kt + a_q * 8;
        const int side = kk >> 10;
        const int kl = kk & 1023;
        const int ofs = sofs[side][a_row];
        *(uint4*)&As[a_row * 40 + a_q * 8] =
            (ofs >= 0) ? *(const uint4*)&nodehb[(size_t)ofs + kl] : z4;
        *(uint4*)&Bs[a_row * 40 + a_q * 8] =
            *(const uint4*)&WcB[(size_t)(g0 + a_row) * K3 + kt + a_q * 8];
      }
      __syncthreads();
      const short8 b = *(const short8*)&Bs[(wave * 16 + l15) * 40 + quad * 8];
#pragma unroll
      for (int mf = 0; mf < 4; ++mf) {
        const short8 a = *(const short8*)&As[(mf * 16 + l15) * 40 + quad * 8];
        acc[mf] = __builtin_amdgcn_mfma_f32_16x16x32_bf16(a, b, acc[mf], 0, 0, 0);
      }
    }
    const int col = g0 + wave * 16 + l15;
#pragma unroll
    for (int mf = 0; mf < 4; ++mf)
#pragma unroll
      for (int i = 0; i < 4; ++i) {
        const int rowm = mf * 16 + quad * 4 + i;
        if (m0 + rowm < cnt) {
          const int node = snode[rowm];
          gB[(size_t)node * H5 + col] += acc[mf][i];
        }
      }
  }
}

// ---------------- per-depth gating ----------------
__global__ void k_gate(const float* __restrict__ gB, const float* __restrict__ cs,
                       const int* __restrict__ meta, float* __restrict__ nodeh,
                       float* __restrict__ nodec, unsigned short* __restrict__ nodehb, int r)
{
  const int* lt = meta + 512;
  const int* li = meta + 1024;
  const int* rt = meta + 1536;
  const int* ri = meta + 2048;
  const int* dcnt = meta + 3088;
  const int* dlist = meta + 3152;
  const int cnt = dcnt[r];
  const int m = blockIdx.x;
  if (m >= cnt) return;
  const int node = dlist[r * 512 + m];
  const int base = node & ~31;
  const int ltv = lt[node], rtv = rt[node];
  const float* clp = (ltv == 2) ? &nodec[(size_t)(base + li[node]) * 1024]
                   : (ltv == 1) ? &cs[(size_t)(base + li[node]) * 1024] : nullptr;
  const float* crp = (rtv == 2) ? &nodec[(size_t)(base + ri[node]) * 1024]
                   : (rtv == 1) ? &cs[(size_t)(base + ri[node]) * 1024] : nullptr;
  const float* g = &gB[(size_t)node * H5];
  for (int j = threadIdx.x; j < 1024; j += 256) {
    const float gi = g[j];
    const float gfl = g[1024 + j];
    const float gfr = g[2048 + j];
    const float gu = g[3072 + j];
    const float go = g[4096 + j];
    const float cl = clp ? clp[j] : 0.0f;
    const float cr = crp ? crp[j] : 0.0f;
    const float c = sigf(gfl) * cl + sigf(gfr) * cr + sigf(gi) * tanhf(gu);
    const float h = sigf(go) * tanhf(c);
    nodeh[(size_t)node * 1024 + j] = h;
    nodec[(size_t)node * 1024 + j] = c;
    nodehb[(size_t)node * 1024 + j] = f2bf(h);
  }
}

// ---------------- gather roots ----------------
__global__ void k_out(const float* __restrict__ nodeh, const float* __restrict__ nodec,
                      float* __restrict__ out)
{
  const int b = blockIdx.x;
  const int tid = threadIdx.x;
  for (int i = tid; i < 1024; i += 256) {
    out[b * 1024 + i] = nodeh[(size_t)(b * 32) * 1024 + i];
    out[16384 + b * 1024 + i] = nodec[(size_t)(b * 32) * 1024 + i];
  }
}

extern "C" void kernel_launch(void* const* d_in, const int* in_sizes, int n_in,
                              void* d_out, int out_size, void* d_ws, size_t ws_size,
                              hipStream_t stream) {
  const float* emb = (const float*)d_in[0];
  const int* len = (const int*)d_in[1];
  const float* Wihf = (const float*)d_in[2];
  const float* Whhf = (const float*)d_in[3];
  const float* bf = (const float*)d_in[4];
  const float* Wihb = (const float*)d_in[5];
  const float* Whhb = (const float*)d_in[6];
  const float* bb = (const float*)d_in[7];
  const float* Wr1 = (const float*)d_in[8];
  const float* Wr2 = (const float*)d_in[9];
  const float* Wc = (const float*)d_in[10];
  const float* bc = (const float*)d_in[11];
  float* out = (float*)d_out;

  float* ws = (float*)d_ws;
  float* Xf = ws;                                         // 1048576 f
  float* Xb = Xf + 1048576;                               // 1048576 f
  float* hs = Xb + 1048576;                               // 524288 f
  float* cs = hs + 524288;                                // 524288 f
  float* E1 = cs + 524288;                                // 131072 f
  unsigned short* U = (unsigned short*)(E1 + 131072);     // 1572864 sh = 786432 f
  float* gB = (float*)U + 786432;                         // 2621440 f
  float* nodeh = gB + 2621440;                            // 524288 f
  float* nodec = nodeh + 524288;                          // 524288 f
  unsigned short* nodehb = (unsigned short*)(nodec + 524288);     // 262144 f
  float* cbuf = (float*)nodehb + 262144;                  // 32768 f
  unsigned short* hbB = (unsigned short*)(cbuf + 32768);  // 32768 sh = 16384 f
  unsigned short* WcB = (unsigned short*)((float*)hbB + 16384);   // 15728640 sh = 7864320 f
  unsigned short* WihfB = WcB + 15728640;                 // 1048576 sh
  unsigned short* WihbB = WihfB + 1048576;
  unsigned short* WhhfB = WihbB + 1048576;
  unsigned short* WhhbB = WhhfB + 1048576;
  unsigned short* embB = WhhbB + 1048576;                 // 262144 sh
  int* meta = (int*)(embB + 262144);                      // ~36K ints

  // zero c/h ping-pong state (contiguous cbuf+hbB) and per-depth counters
  k_zero<<<192, 256, 0, stream>>>(cbuf, 49152);
  k_zero<<<1, 64, 0, stream>>>((float*)(meta + 3088), 64);
  // bf16 conversions (one launch)
  k_conv6<<<dim3(1920, 6), 256, 0, stream>>>(
      Wc, WcB, 15728640, Wihf, WihfB, 1048576, Wihb, WihbB, 1048576,
      Whhf, WhhfB, 1048576, Whhb, WhhbB, 1048576, emb, embB, 262144);
  // rank projection (f32, small)
  k_gemm<<<dim3(4, 8), 256, 0, stream>>>(emb, 512, Wr1, 513, E1, 256, 512);
  // input projections (bf16 MFMA, both dirs)
  k_xproj<<<dim3(16, 4, 2), 256, 0, stream>>>(embB, WihfB, WihbB, Xf, Xb);
  // recurrent scan (MFMA steps)
  for (int t = 0; t < SL; ++t)
    k_stepm<<<dim3(32, 2), 256, 0, stream>>>(Xf, Xb, WhhfB, WhhbB, bf, bb, len,
                                             hbB, cbuf, hs, cs, t);
  // tree structure + depth/link lists
  k_tree<<<16, 256, 0, stream>>>(E1, Wr1, Wr2, len, meta);
  // precomputable part of every compose (own + leaf children)
  k_ubuild<<<dim3(32, 16), 256, 0, stream>>>(hs, meta, U);
  k_mfma_gemm<<<320, 256, 0, stream>>>(U, WcB, bc, gB);
  // depth-ordered compose rounds
  for (int r = 1; r <= 31; ++r) {
    k_linkgemm<<<dim3(80, 2), 256, 0, stream>>>(WcB, meta, nodehb, gB, r);
    k_gate<<<512, 256, 0, stream>>>(gB, cs, meta, nodeh, nodec, nodehb, r);
  }
  k_out<<<16, 256, 0, stream>>>(nodeh, nodec, out);
}